// Round 12
// baseline (220.232 us; speedup 1.0000x reference)
//
#include <hip/hip_runtime.h>
#include <cstdint>
#include <cstddef>

typedef float  f32x4   __attribute__((ext_vector_type(4)));
typedef __bf16 bf16x8  __attribute__((ext_vector_type(8)));
typedef short  short8  __attribute__((ext_vector_type(8)));
typedef short  short4v __attribute__((ext_vector_type(4)));
typedef float  float4v __attribute__((ext_vector_type(4)));

#define DEVI __device__ __forceinline__

constexpr int Bb = 32, Nn = 577, Cc = 768, Hh = 12, DK = 64;
constexpr int Mm   = Bb * Nn;     // 18464 rows
constexpr int NQKV = 3 * Cc;      // 2304 fused QKV output cols
constexpr int NKPAD = 640;        // padded key count (10 tiles of 64)
constexpr int NT = 10;
#define QSCALE 0.1803368926f      // 0.125 * log2(e) folded into Q

DEVI short f2bf(float f) {
  __bf16 h = (__bf16)f;
  short s;
  __builtin_memcpy(&s, &h, 2);
  return s;
}

DEVI void gload16(const short* g, short* l) {   // async global->LDS, 16B/lane
  __builtin_amdgcn_global_load_lds(
      (const __attribute__((address_space(1))) void*)g,
      (__attribute__((address_space(3))) void*)l, 16, 0, 0);
}

DEVI f32x4 mfma16(bf16x8 a, bf16x8 b, f32x4 c) {
  return __builtin_amdgcn_mfma_f32_16x16x32_bf16(a, b, c, 0, 0, 0);
}

// XCD-bijective chunking over Triton-style grouped ordering.
DEVI void remap_grouped(int bid, int nbm, int nbn, int GM, int& bm, int& bn) {
  const int nwg = nbm * nbn;
  const int xcd = bid & 7, j = bid >> 3;
  const int q = nwg >> 3, r = nwg & 7;
  int wg = (xcd < r ? xcd * (q + 1) : r * (q + 1) + (xcd - r) * q) + j;
  const int per = GM * nbn;
  int grp = wg / per;
  int first = grp * GM;
  int sz = min(GM, nbm - first);
  int rem = wg - grp * per;
  bm = first + rem % sz;
  bn = rem / sz;
}

// ---------------- conversion kernels ----------------

__global__ void k_cvt(const float* __restrict__ in, short* __restrict__ out, int n4) {
  int i = blockIdx.x * 256 + threadIdx.x;
  if (i >= n4) return;
  float4v v = *(const float4v*)(in + (size_t)i * 4);
  short4v o;
#pragma unroll
  for (int j = 0; j < 4; ++j) o[j] = f2bf(v[j]);
  *(short4v*)(out + (size_t)i * 4) = o;
}

__global__ void k_cvt_wqkv(const float* __restrict__ Wq, const float* __restrict__ Wk,
                           const float* __restrict__ Wv, short* __restrict__ out) {
  int i = blockIdx.x * 256 + threadIdx.x;
  int e = i * 4;
  if (e >= NQKV * Cc) return;
  const int WSZ = Cc * Cc;
  const float* src;
  if (e < WSZ)          src = Wq + e;
  else if (e < 2 * WSZ) src = Wk + (e - WSZ);
  else                  src = Wv + (e - 2 * WSZ);
  float4v v = *(const float4v*)src;
  short4v o;
#pragma unroll
  for (int j = 0; j < 4; ++j) o[j] = f2bf(v[j]);
  *(short4v*)(out + (size_t)e) = o;
}

#define WAITV(N) asm volatile("s_waitcnt vmcnt(" #N ")" ::: "memory")

// ============ core B2: [256][64]-row tiles, 8-granule XOR (0-conflict), MERGED
// phases: one phase = one (buf, kk) = 32 MFMA (all 8 M-frags x 4 N-frags).
// Barriers per block: 192 -> 96 (R11 PMC: ~700cy/phase sync overhead vs 155cy
// MFMA -> barrier-bound). Stage stream + WAITV issue-prefixes identical to the
// R10/R11-validated 8-phase ledger (waits moved later in issue order only,
// same N -> strictly safer for consumers; regions unchanged).
#define GPH2(BUF, KK, STAGE, WAIT)                                         \
  {                                                                        \
    const short* Ab_ = Al + (BUF) * 16384;                                 \
    const short* Bb_ = Bl + (BUF) * 16384;                                 \
    bf16x8 af_[8], bf_[4];                                                 \
    _Pragma("unroll")                                                      \
    for (int m_ = 0; m_ < 8; ++m_)                                         \
      af_[m_] = *(const bf16x8*)(Ab_ + (offA[m_] ^ ((KK) * 32)));          \
    _Pragma("unroll")                                                      \
    for (int n_ = 0; n_ < 4; ++n_)                                         \
      bf_[n_] = *(const bf16x8*)(Bb_ + (offB[n_] ^ ((KK) * 32)));          \
    STAGE;                                                                 \
    WAIT;                                                                  \
    __builtin_amdgcn_s_barrier();                                          \
    __builtin_amdgcn_s_setprio(1);                                         \
    _Pragma("unroll")                                                      \
    for (int m_ = 0; m_ < 8; ++m_)                                         \
      _Pragma("unroll")                                                    \
      for (int n_ = 0; n_ < 4; ++n_)                                       \
        acc[m_][n_] = mfma16(af_[m_], bf_[n_], acc[m_][n_]);               \
    __builtin_amdgcn_s_setprio(0);                                         \
    __builtin_amdgcn_s_barrier();                                          \
  }

DEVI void gemm256b(const short* __restrict__ A, const short* __restrict__ Bm,
                   int arows, int bm, int bn,
                   short* Al, short* Bl, f32x4 acc[8][4]) {
  const int tid = threadIdx.x;               // 0..511
  const int lane = tid & 63, w = tid >> 6;
  const int wm = w >> 2, wn = w & 3;
  const int qi = lane & 15, g = lane >> 4;

#pragma unroll
  for (int m = 0; m < 8; ++m)
#pragma unroll
    for (int n = 0; n < 4; ++n) acc[m][n] = (f32x4)0.0f;

  const int rloc = tid >> 3, c8 = tid & 7;
  const int gswz = (c8 ^ (rloc & 7)) * 8;
  const short* pA[4];
  const short* pB[4];
#pragma unroll
  for (int s = 0; s < 4; ++s) {
    int ra = bm * 256 + s * 64 + rloc; if (ra > arows - 1) ra = arows - 1;
    pA[s] = A  + (size_t)ra * Cc + gswz;
    pB[s] = Bm + (size_t)(bn * 256 + s * 64 + rloc) * Cc + gswz;
  }
  auto stA = [&](int buf, int s, int co) {
    gload16(pA[s] + co, Al + buf * 16384 + s * 4096 + tid * 8);
  };
  auto stB = [&](int buf, int s, int co) {
    gload16(pB[s] + co, Bl + buf * 16384 + s * 4096 + tid * 8);
  };

  int offA[8], offB[4];
#pragma unroll
  for (int m = 0; m < 8; ++m) {
    int r = wm * 128 + m * 16 + qi;
    offA[m] = r * 64 + ((g ^ (r & 7)) * 8);
  }
#pragma unroll
  for (int n = 0; n < 4; ++n) {
    int r = wn * 64 + n * 16 + qi;
    offB[n] = r * 64 + ((g ^ (r & 7)) * 8);
  }

  // prologue: tile0 A+B (8 segs), tile1 B{0,1}; WAITV(2) -> tile0 resident
  stA(0, 0, 0); stA(0, 1, 0); stA(0, 2, 0); stA(0, 3, 0);
  stB(0, 0, 0); stB(0, 1, 0); stB(0, 2, 0); stB(0, 3, 0);
  stB(1, 0, 64); stB(1, 1, 64);
  WAITV(2);
  __builtin_amdgcn_s_barrier();

#pragma unroll 1
  for (int i = 0; i < 5; ++i) {
    const int cb1  = 64 + 128 * i;     // tile 2i+1 cols
    const int cb0n = cb1 + 64;         // tile 2i+2
    const int cb1n = cb1 + 128;        // tile 2i+3
    GPH2(0, 0, (stB(1, 2, cb1),  stB(1, 3, cb1),
                stA(1, 0, cb1),  stA(1, 2, cb1)),  (void)0);
    GPH2(0, 1, (stA(1, 1, cb1),  stA(1, 3, cb1),
                stA(0, 0, cb0n), stA(0, 2, cb0n)), WAITV(4));
    GPH2(1, 0, (stA(0, 1, cb0n), stA(0, 3, cb0n),
                stB(0, 0, cb0n), stB(0, 1, cb0n)), WAITV(4));
    GPH2(1, 1, (stB(0, 2, cb0n), stB(0, 3, cb0n),
                stB(1, 0, cb1n), stB(1, 1, cb1n)), WAITV(2));
  }
  // tail: tiles 10 (buf0), 11 (buf1); finish staging tile 11 (col 704)
  GPH2(0, 0, (stB(1, 2, 704), stB(1, 3, 704),
              stA(1, 0, 704), stA(1, 2, 704)), (void)0);
  GPH2(0, 1, (stA(1, 1, 704), stA(1, 3, 704)), WAITV(2));
  GPH2(1, 0, (void)0, WAITV(0));
  GPH2(1, 1, (void)0, (void)0);
}

// GEMM1: x_bf16 @ [Wq;Wk;Wv]^T + b -> q/k/v [B,H,N,64] bf16 (Q scaled).
__global__ __launch_bounds__(512) void k_gemm_qkv(
    const short* __restrict__ A, const short* __restrict__ Bm,
    const float* __restrict__ bq, const float* __restrict__ bk, const float* __restrict__ bv,
    short* __restrict__ qv, short* __restrict__ kv, short* __restrict__ vv) {
  __shared__ short Al[2 * 16384];
  __shared__ short Bl[2 * 16384];
  int bm, bn;
  remap_grouped((int)blockIdx.x, (Mm + 255) / 256, NQKV / 256, 4, bm, bn);
  f32x4 acc[8][4];
  gemm256b(A, Bm, Mm, bm, bn, Al, Bl, acc);

  const int lane = threadIdx.x & 63, w = threadIdx.x >> 6;
  const int wm = w >> 2, wn = w & 3;
  const int qi = lane & 15, g = lane >> 4;
  const int cb = bn * 256 + wn * 64;         // 64-aligned -> single (proj, head)
  const int proj = cb / Cc;
  const int within = cb - proj * Cc;
  const float* bias = proj == 0 ? bq : proj == 1 ? bk : bv;
  short* dst = proj == 0 ? qv : proj == 1 ? kv : vv;
  const float sc = proj == 0 ? QSCALE : 1.0f;
  const int hh = within >> 6;
  float bvv[4];
#pragma unroll
  for (int n = 0; n < 4; ++n) bvv[n] = bias[within + n * 16 + qi];
#pragma unroll
  for (int m = 0; m < 8; ++m)
#pragma unroll
    for (int r = 0; r < 4; ++r) {
      int row = bm * 256 + wm * 128 + m * 16 + g * 4 + r;
      if (row < Mm) {
        int b = row / Nn;
        int nn = row - b * Nn;
        size_t base = ((size_t)(b * Hh + hh) * Nn + nn) * DK;
#pragma unroll
        for (int n = 0; n < 4; ++n)
          dst[base + n * 16 + qi] = f2bf((acc[m][n][r] + bvv[n]) * sc);
      }
    }
}

// GEMM2: attn_out_bf16 @ Wo^T + bo -> fp32 out [M][768]
__global__ __launch_bounds__(512) void k_gemm_out(
    const short* __restrict__ A, const short* __restrict__ Bm,
    const float* __restrict__ bo, float* __restrict__ out) {
  __shared__ short Al[2 * 16384];
  __shared__ short Bl[2 * 16384];
  int bm, bn;
  remap_grouped((int)blockIdx.x, (Mm + 255) / 256, Cc / 256, 8, bm, bn);
  f32x4 acc[8][4];
  gemm256b(A, Bm, Mm, bm, bn, Al, Bl, acc);

  const int lane = threadIdx.x & 63, w = threadIdx.x >> 6;
  const int wm = w >> 2, wn = w & 3;
  const int qi = lane & 15, g = lane >> 4;
  const int cb = bn * 256 + wn * 64;
  float bvv[4];
#pragma unroll
  for (int n = 0; n < 4; ++n) bvv[n] = bo[cb + n * 16 + qi];
#pragma unroll
  for (int m = 0; m < 8; ++m)
#pragma unroll
    for (int r = 0; r < 4; ++r) {
      int row = bm * 256 + wm * 128 + m * 16 + g * 4 + r;
      if (row < Mm) {
#pragma unroll
        for (int n = 0; n < 4; ++n)
          out[(size_t)row * Cc + cb + n * 16 + qi] = acc[m][n][r] + bvv[n];
      }
    }
}

// V transpose: v [B,H,577,64] -> vt [B,H,64,640], zero-padded keys 577..639
__global__ __launch_bounds__(256) void k_transpose_v(const short* __restrict__ v,
                                                     short* __restrict__ vt) {
  __shared__ short t[64 * 72];
  const int bid = blockIdx.x;
  const int ch = bid % NT, bh = bid / NT;
  const int tid = threadIdx.x;
  const short* vb = v + (size_t)bh * Nn * DK;
#pragma unroll
  for (int i = 0; i < 2; ++i) {
    int gi = i * 256 + tid;
    int r = gi >> 3, c = gi & 7;
    int n = ch * 64 + r;
    short8 val;
#pragma unroll
    for (int j = 0; j < 8; ++j) val[j] = 0;
    if (n < Nn) val = *(const short8*)(vb + (size_t)n * DK + c * 8);
    *(short8*)(t + r * 72 + c * 8) = val;
  }
  __syncthreads();
  short* ob = vt + (size_t)bh * DK * NKPAD + ch * 64;
#pragma unroll
  for (int i = 0; i < 2; ++i) {
    int gi = i * 256 + tid;
    int d = gi >> 3, cg = gi & 7;
    short8 o;
#pragma unroll
    for (int j = 0; j < 8; ++j) o[j] = t[(cg * 8 + j) * 72 + d];
    *(short8*)(ob + (size_t)d * NKPAD + cg * 8) = o;
  }
}

// Flash attention: swapped-QK^T, no-max softmax, 2 q-tiles/block with
// (a) K/V fragments read from LDS ONCE per tile (register-shared across both
// q-tiles) and (b) ONE shared P buffer (40KB LDS -> 4 blocks/CU). No
// min-waves clause (R9 spill lesson). Unchanged from R11 (clean attribution).
__global__ __launch_bounds__(256) void k_attn(const short* __restrict__ q,
                                              const short* __restrict__ k,
                                              const short* __restrict__ vt,
                                              short* __restrict__ ao) {
  __shared__ short Ks[2][64 * 64];
  __shared__ short Vs[2][64 * 64];
  __shared__ short Ps[4][16 * 64];     // per-wave, shared by both q-tiles
  int bid = (int)blockIdx.x;
  bid = (bid & 7) * 240 + (bid >> 3);  // XCD swizzle: 1920 = 8*240, bijective
  const int qtp = bid % 5, bh = bid / 5;
  const int qt0 = qtp * 2;
  const int bb = bh / Hh, hh = bh - bb * Hh;
  const int tid = threadIdx.x, lane = tid & 63, w = tid >> 6;
  const int qi = lane & 15, g = lane >> 4;

  const short* qb  = q  + (size_t)bh * Nn * DK;
  const short* kb  = k  + (size_t)bh * Nn * DK;
  const short* vtb = vt + (size_t)bh * DK * NKPAD;

  const int qrow = qt0 * 64 + w * 16 + qi;
  const bf16x8 qf0a = *(const bf16x8*)(qb + (size_t)qrow * DK + g * 8);
  const bf16x8 qf1a = *(const bf16x8*)(qb + (size_t)qrow * DK + 32 + g * 8);
  const bf16x8 qf0b = *(const bf16x8*)(qb + (size_t)(qrow + 64) * DK + g * 8);
  const bf16x8 qf1b = *(const bf16x8*)(qb + (size_t)(qrow + 64) * DK + 32 + g * 8);

  const int r0 = tid >> 3, cc = tid & 7;
  const int cs0 = (cc ^ (r0 & 7)) * 8;
  const short* kg = kb + r0 * DK + cs0;
  const short* vg = vtb + (size_t)r0 * NKPAD + cs0;
  short* const Kd0 = &Ks[0][w * 512]; short* const Kd1 = &Ks[1][w * 512];
  short* const Vd0 = &Vs[0][w * 512]; short* const Vd1 = &Vs[1][w * 512];

  auto stage = [&](short* Kd, short* Vd) {
    gload16(kg, Kd);          gload16(kg + 2048,  Kd + 2048);
    gload16(vg, Vd);          gload16(vg + 20480, Vd + 2048);
    kg += 4096;               vg += 64;
  };

  const int swq = qi & 7;
  const short* const KF00 = &Ks[0][qi * 64 + ((g    ) ^ swq) * 8];
  const short* const KF01 = &Ks[0][qi * 64 + ((g + 4) ^ swq) * 8];
  const short* const KF10 = &Ks[1][qi * 64 + ((g    ) ^ swq) * 8];
  const short* const KF11 = &Ks[1][qi * 64 + ((g + 4) ^ swq) * 8];
  const short* const VF00 = &Vs[0][qi * 64 + ((g    ) ^ swq) * 8];
  const short* const VF01 = &Vs[0][qi * 64 + ((g + 4) ^ swq) * 8];
  const short* const VF10 = &Vs[1][qi * 64 + ((g    ) ^ swq) * 8];
  const short* const VF11 = &Vs[1][qi * 64 + ((g + 4) ^ swq) * 8];
  short* const PW0 = &Ps[w][qi * 64 + (((0  + g) ^ (swq << 1)) << 2)];
  short* const PW1 = &Ps[w][qi * 64 + (((4  + g) ^ (swq << 1)) << 2)];
  short* const PW2 = &Ps[w][qi * 64 + (((8  + g) ^ (swq << 1)) << 2)];
  short* const PW3 = &Ps[w][qi * 64 + (((12 + g) ^ (swq << 1)) << 2)];
  const short* const PR0 = &Ps[w][qi * 64 + ((g    ) ^ swq) * 8];
  const short* const PR1 = &Ps[w][qi * 64 + ((g + 4) ^ swq) * 8];

  f32x4 accA[4], accB[4];
#pragma unroll
  for (int nd = 0; nd < 4; ++nd) { accA[nd] = (f32x4)0.0f; accB[nd] = (f32x4)0.0f; }
  float lsA = 0.f, lsB = 0.f;

  auto smax = [&](f32x4* s, float& ls, bool last) {
    if (last) {                        // keys 577..639 invalid
#pragma unroll
      for (int ni = 0; ni < 4; ++ni)
#pragma unroll
        for (int r = 0; r < 4; ++r)
          if (ni || r) s[ni][r] = -1e30f;
      if (g) s[0][0] = -1e30f;
    }
    float rs = 0.f;
    short4v pk0, pk1, pk2, pk3;
#pragma unroll
    for (int r = 0; r < 4; ++r) { float p = exp2f(s[0][r]); rs += p; pk0[r] = f2bf(p); }
#pragma unroll
    for (int r = 0; r < 4; ++r) { float p = exp2f(s[1][r]); rs += p; pk1[r] = f2bf(p); }
#pragma unroll
    for (int r = 0; r < 4; ++r) { float p = exp2f(s[2][r]); rs += p; pk2[r] = f2bf(p); }
#pragma unroll
    for (int r = 0; r < 4; ++r) { float p = exp2f(s[3][r]); rs += p; pk3[r] = f2bf(p); }
    *(short4v*)PW0 = pk0; *(short4v*)PW1 = pk1;
    *(short4v*)PW2 = pk2; *(short4v*)PW3 = pk3;
    rs += __shfl_xor(rs, 16);
    rs += __shfl_xor(rs, 32);
    ls += rs;
  };

  auto tilestep = [&](const short* Kf0, const short* Kf1,
                      const short* Vf0, const short* Vf1, bool last) {
    f32x4 sA[4], sB[4];
#pragma unroll
    for (int ni = 0; ni < 4; ++ni) { sA[ni] = (f32x4)0.0f; sB[ni] = (f32x4)0.0f; }
    {
      bf16x8 kf[4];
#pragma unroll
      for (int ni = 0; ni < 4; ++ni) kf[ni] = *(const bf16x8*)(Kf0 + ni * 1024);
#pragma unroll
      for (int ni = 0; ni < 4; ++ni) sA[ni] = mfma16(kf[ni], qf0a, sA[ni]);
#pragma unroll
      for (int ni = 0; ni < 4; ++ni) sB[ni] = mfma16(kf[ni], qf0b, sB[ni]);
#pragma unroll
      for (int ni = 0; ni < 4; ++ni) kf[ni] = *(const bf16x8*)(Kf1 + ni * 1024);
#pragma unroll
      for (int ni = 0; ni < 4; ++ni) sA[ni] = mfma16(kf[ni], qf1a, sA[ni]);
#pragma unroll
      for (int ni = 0; ni < 4; ++ni) sB[ni] = mfma16(kf[ni], qf1b, sB[ni]);
    }
    smax(sA, lsA, last);
    bf16x8 paA0 = *(const bf16x8*)PR0;   // reads issued before P is overwritten
    bf16x8 paA1 = *(const bf16x8*)PR1;
    smax(sB, lsB, last);
    bf16x8 paB0 = *(const bf16x8*)PR0;
    bf16x8 paB1 = *(const bf16x8*)PR1;
    {
      bf16x8 vf[4];
#pragma unroll
      for (int nd = 0; nd < 4; ++nd) vf[nd] = *(const bf16x8*)(Vf0 + nd * 1024);
#pragma unroll
      for (int nd = 0; nd < 4; ++nd) accA[nd] = mfma16(paA0, vf[nd], accA[nd]);
#pragma unroll
      for (int nd = 0; nd < 4; ++nd) accB[nd] = mfma16(paB0, vf[nd], accB[nd]);
#pragma unroll
      for (int nd = 0; nd < 4; ++nd) vf[nd] = *(const bf16x8*)(Vf1 + nd * 1024);
#pragma unroll
      for (int nd = 0; nd < 4; ++nd) accA[nd] = mfma16(paA1, vf[nd], accA[nd]);
#pragma unroll
      for (int nd = 0; nd < 4; ++nd) accB[nd] = mfma16(paB1, vf[nd], accB[nd]);
    }
  };

  stage(Kd0, Vd0);
  __syncthreads();
#pragma unroll 1
  for (int t2 = 0; t2 < 5; ++t2) {
    stage(Kd1, Vd1);
    tilestep(KF00, KF01, VF00, VF01, false);
    __syncthreads();
    if (t2 < 4) {
      stage(Kd0, Vd0);
      tilestep(KF10, KF11, VF10, VF11, false);
      __syncthreads();
    }
  }
  tilestep(KF10, KF11, VF10, VF11, true);

  auto epi = [&](f32x4* accd, float ls, int qt) {
    float ls4[4];
#pragma unroll
    for (int r = 0; r < 4; ++r) ls4[r] = __shfl(ls, (g << 2) + r);
#pragma unroll
    for (int r = 0; r < 4; ++r) {
      int qr = qt * 64 + w * 16 + (g << 2) + r;
      if (qr < Nn) {
        float inv = 1.0f / ls4[r];
        size_t base = ((size_t)(bb * Nn + qr)) * Cc + hh * DK;
#pragma unroll
        for (int nd = 0; nd < 4; ++nd)
          ao[base + nd * 16 + qi] = f2bf(accd[nd][r] * inv);
      }
    }
  };
  epi(accA, lsA, qt0);
  epi(accB, lsB, qt0 + 1);
}

// ---------------- launch ----------------

extern "C" void kernel_launch(void* const* d_in, const int* in_sizes, int n_in,
                              void* d_out, int out_size, void* d_ws, size_t ws_size,
                              hipStream_t stream) {
  const float* x  = (const float*)d_in[0];
  const float* Wq = (const float*)d_in[1];
  const float* bq = (const float*)d_in[2];
  const float* Wk = (const float*)d_in[3];
  const float* bk = (const float*)d_in[4];
  const float* Wv = (const float*)d_in[5];
  const float* bv = (const float*)d_in[6];
  const float* Wo = (const float*)d_in[7];
  const float* bo = (const float*)d_in[8];
  float* out = (float*)d_out;

  char* ws = (char*)d_ws;
  size_t off = 0;
  auto alloc = [&](size_t bytes) {
    char* p = ws + off;
    off += (bytes + 255) & ~(size_t)255;
    return p;
  };
  short* xb   = (short*)alloc((size_t)Mm * Cc * 2);          // x bf16 (reused as attn_out)
  short* wqkv = (short*)alloc((size_t)NQKV * Cc * 2);
  short* wob  = (short*)alloc((size_t)Cc * Cc * 2);
  short* qb   = (short*)alloc((size_t)Bb * Hh * Nn * DK * 2);
  short* kb   = (short*)alloc((size_t)Bb * Hh * Nn * DK * 2);
  short* vb   = (short*)alloc((size_t)Bb * Hh * Nn * DK * 2);
  short* vtb  = (short*)alloc((size_t)Bb * Hh * DK * NKPAD * 2);
  short* aob  = xb;   // x_bf16 dead after GEMM1; alias for attn output

  k_cvt<<<(Mm * Cc / 4 + 255) / 256, 256, 0, stream>>>(x, xb, Mm * Cc / 4);
  k_cvt_wqkv<<<(NQKV * Cc / 4 + 255) / 256, 256, 0, stream>>>(Wq, Wk, Wv, wqkv);
  k_cvt<<<(Cc * Cc / 4 + 255) / 256, 256, 0, stream>>>(Wo, wob, Cc * Cc / 4);

  const int nbm = (Mm + 255) / 256;        // 73
  k_gemm_qkv<<<nbm * (NQKV / 256), 512, 0, stream>>>(xb, wqkv, bq, bk, bv, qb, kb, vb);

  k_transpose_v<<<Bb * Hh * NT, 256, 0, stream>>>(vb, vtb);

  k_attn<<<Bb * Hh * 5, 256, 0, stream>>>(qb, kb, vtb, aob);

  k_gemm_out<<<nbm * (Cc / 256), 512, 0, stream>>>(aob, wob, bo, out);
}

// Round 13
// 212.530 us; speedup vs baseline: 1.0362x; 1.0362x over previous
//
#include <hip/hip_runtime.h>
#include <cstdint>
#include <cstddef>

typedef float  f32x4   __attribute__((ext_vector_type(4)));
typedef __bf16 bf16x8  __attribute__((ext_vector_type(8)));
typedef short  short8  __attribute__((ext_vector_type(8)));
typedef short  short4v __attribute__((ext_vector_type(4)));
typedef float  float4v __attribute__((ext_vector_type(4)));

#define DEVI __device__ __forceinline__

constexpr int Bb = 32, Nn = 577, Cc = 768, Hh = 12, DK = 64;
constexpr int Mm   = Bb * Nn;     // 18464 rows
constexpr int NQKV = 3 * Cc;      // 2304 fused QKV output cols
constexpr int NKPAD = 640;        // padded key count (10 tiles of 64)
constexpr int NT = 10;
#define QSCALE 0.1803368926f      // 0.125 * log2(e) folded into Q

DEVI short f2bf(float f) {
  __bf16 h = (__bf16)f;
  short s;
  __builtin_memcpy(&s, &h, 2);
  return s;
}

DEVI void gload16(const short* g, short* l) {   // async global->LDS, 16B/lane
  __builtin_amdgcn_global_load_lds(
      (const __attribute__((address_space(1))) void*)g,
      (__attribute__((address_space(3))) void*)l, 16, 0, 0);
}

DEVI f32x4 mfma16(bf16x8 a, bf16x8 b, f32x4 c) {
  return __builtin_amdgcn_mfma_f32_16x16x32_bf16(a, b, c, 0, 0, 0);
}

// XCD-bijective chunking over Triton-style grouped ordering.
DEVI void remap_grouped(int bid, int nbm, int nbn, int GM, int& bm, int& bn) {
  const int nwg = nbm * nbn;
  const int xcd = bid & 7, j = bid >> 3;
  const int q = nwg >> 3, r = nwg & 7;
  int wg = (xcd < r ? xcd * (q + 1) : r * (q + 1) + (xcd - r) * q) + j;
  const int per = GM * nbn;
  int grp = wg / per;
  int first = grp * GM;
  int sz = min(GM, nbm - first);
  int rem = wg - grp * per;
  bm = first + rem % sz;
  bn = rem / sz;
}

// ---------------- single fused conversion kernel (x, Wqkv, Wo -> bf16) --------

__global__ void k_cvt_all(const float* __restrict__ x,
                          const float* __restrict__ Wq, const float* __restrict__ Wk,
                          const float* __restrict__ Wv, const float* __restrict__ Wo,
                          short* __restrict__ xb, short* __restrict__ wqkv,
                          short* __restrict__ wob) {
  const int NX4   = Mm * Cc / 4;        // 3,545,088 float4s of x
  const int WSZ4  = Cc * Cc / 4;        // 147,456 per weight matrix
  int i = blockIdx.x * 256 + threadIdx.x;
  const float* src;
  short* dst;
  int e;
  if (i < NX4) { src = x; dst = xb; e = i; }
  else {
    int j = i - NX4;
    if (j < WSZ4)          { src = Wq; dst = wqkv;                e = j; }
    else if (j < 2 * WSZ4) { src = Wk; dst = wqkv + WSZ4 * 4;     e = j - WSZ4; }
    else if (j < 3 * WSZ4) { src = Wv; dst = wqkv + 2 * WSZ4 * 4; e = j - 2 * WSZ4; }
    else if (j < 4 * WSZ4) { src = Wo; dst = wob;                 e = j - 3 * WSZ4; }
    else return;
  }
  float4v v = *(const float4v*)(src + (size_t)e * 4);
  short4v o;
#pragma unroll
  for (int t = 0; t < 4; ++t) o[t] = f2bf(v[t]);
  *(short4v*)(dst + (size_t)e * 4) = o;
}

#define WAITV(N) asm volatile("s_waitcnt vmcnt(" #N ")" ::: "memory")

// ============ core B: [256][64]-row tiles, 8-granule XOR (0-conflict), 8-phase
// schedule (R11-validated best: 88.3us, conflicts 0; R12's merged 4-phase
// variant regressed to 95 -> reverted).
#define GPH(BUF, KK, MH, STAGE, WAIT)                                      \
  {                                                                        \
    const short* Ab_ = Al + (BUF) * 16384;                                 \
    const short* Bb_ = Bl + (BUF) * 16384;                                 \
    bf16x8 af_[4];                                                         \
    _Pragma("unroll")                                                      \
    for (int m_ = 0; m_ < 4; ++m_)                                         \
      af_[m_] = *(const bf16x8*)(Ab_ + (offA[(MH) * 4 + m_] ^ ((KK) * 32))); \
    if ((MH) == 0) {                                                       \
      _Pragma("unroll")                                                    \
      for (int n_ = 0; n_ < 4; ++n_)                                       \
        bfr[n_] = *(const bf16x8*)(Bb_ + (offB[n_] ^ ((KK) * 32)));        \
    }                                                                      \
    STAGE;                                                                 \
    WAIT;                                                                  \
    __builtin_amdgcn_s_barrier();                                          \
    __builtin_amdgcn_s_setprio(1);                                         \
    _Pragma("unroll")                                                      \
    for (int m_ = 0; m_ < 4; ++m_)                                         \
      _Pragma("unroll")                                                    \
      for (int n_ = 0; n_ < 4; ++n_)                                       \
        acc[(MH) * 4 + m_][n_] = mfma16(af_[m_], bfr[n_], acc[(MH) * 4 + m_][n_]); \
    __builtin_amdgcn_s_setprio(0);                                         \
    __builtin_amdgcn_s_barrier();                                          \
  }

DEVI void gemm256b(const short* __restrict__ A, const short* __restrict__ Bm,
                   int arows, int bm, int bn,
                   short* Al, short* Bl, f32x4 acc[8][4]) {
  const int tid = threadIdx.x;               // 0..511
  const int lane = tid & 63, w = tid >> 6;
  const int wm = w >> 2, wn = w & 3;
  const int qi = lane & 15, g = lane >> 4;

#pragma unroll
  for (int m = 0; m < 8; ++m)
#pragma unroll
    for (int n = 0; n < 4; ++n) acc[m][n] = (f32x4)0.0f;

  const int rloc = tid >> 3, c8 = tid & 7;
  const int gswz = (c8 ^ (rloc & 7)) * 8;
  const short* pA[4];
  const short* pB[4];
#pragma unroll
  for (int s = 0; s < 4; ++s) {
    int ra = bm * 256 + s * 64 + rloc; if (ra > arows - 1) ra = arows - 1;
    pA[s] = A  + (size_t)ra * Cc + gswz;
    pB[s] = Bm + (size_t)(bn * 256 + s * 64 + rloc) * Cc + gswz;
  }
  auto stA = [&](int buf, int s, int co) {
    gload16(pA[s] + co, Al + buf * 16384 + s * 4096 + tid * 8);
  };
  auto stB = [&](int buf, int s, int co) {
    gload16(pB[s] + co, Bl + buf * 16384 + s * 4096 + tid * 8);
  };

  int offA[8], offB[4];
#pragma unroll
  for (int m = 0; m < 8; ++m) {
    int r = wm * 128 + m * 16 + qi;
    offA[m] = r * 64 + ((g ^ (r & 7)) * 8);
  }
#pragma unroll
  for (int n = 0; n < 4; ++n) {
    int r = wn * 64 + n * 16 + qi;
    offB[n] = r * 64 + ((g ^ (r & 7)) * 8);
  }
  bf16x8 bfr[4];

  // prologue: tile0 A+B (8 segs), tile1 B{0,1}; WAITV(2) -> tile0 resident
  stA(0, 0, 0); stA(0, 1, 0); stA(0, 2, 0); stA(0, 3, 0);
  stB(0, 0, 0); stB(0, 1, 0); stB(0, 2, 0); stB(0, 3, 0);
  stB(1, 0, 64); stB(1, 1, 64);
  WAITV(2);
  __builtin_amdgcn_s_barrier();

#pragma unroll 1
  for (int i = 0; i < 5; ++i) {
    const int cb1  = 64 + 128 * i;     // tile 2i+1 cols
    const int cb0n = cb1 + 64;         // tile 2i+2
    const int cb1n = cb1 + 128;        // tile 2i+3
    GPH(0, 0, 0, (stB(1, 2, cb1),  stB(1, 3, cb1)),  (void)0);
    GPH(0, 0, 1, (stA(1, 0, cb1),  stA(1, 2, cb1)),  (void)0);
    GPH(0, 1, 0, (stA(1, 1, cb1),  stA(1, 3, cb1)),  (void)0);
    GPH(0, 1, 1, (stA(0, 0, cb0n), stA(0, 2, cb0n)), WAITV(4));
    GPH(1, 0, 0, (stA(0, 1, cb0n), stA(0, 3, cb0n)), WAITV(4));
    GPH(1, 0, 1, (stB(0, 0, cb0n), stB(0, 1, cb0n)), (void)0);
    GPH(1, 1, 0, (stB(0, 2, cb0n), stB(0, 3, cb0n)), (void)0);
    GPH(1, 1, 1, (stB(1, 0, cb1n), stB(1, 1, cb1n)), WAITV(2));
  }
  // tail: tiles 10 (buf0), 11 (buf1); finish staging tile 11 (col 704)
  GPH(0, 0, 0, (stB(1, 2, 704), stB(1, 3, 704)), (void)0);
  GPH(0, 0, 1, (stA(1, 0, 704), stA(1, 2, 704)), (void)0);
  GPH(0, 1, 0, (stA(1, 1, 704), stA(1, 3, 704)), (void)0);
  GPH(0, 1, 1, (void)0, WAITV(2));
  GPH(1, 0, 0, (void)0, WAITV(0));
  GPH(1, 0, 1, (void)0, (void)0);
  GPH(1, 1, 0, (void)0, (void)0);
  GPH(1, 1, 1, (void)0, (void)0);
}

// GEMM1: x_bf16 @ [Wq;Wk;Wv]^T + b -> q/k/v [B,H,N,64] bf16 (Q scaled).
__global__ __launch_bounds__(512) void k_gemm_qkv(
    const short* __restrict__ A, const short* __restrict__ Bm,
    const float* __restrict__ bq, const float* __restrict__ bk, const float* __restrict__ bv,
    short* __restrict__ qv, short* __restrict__ kv, short* __restrict__ vv) {
  __shared__ short Al[2 * 16384];
  __shared__ short Bl[2 * 16384];
  int bm, bn;
  remap_grouped((int)blockIdx.x, (Mm + 255) / 256, NQKV / 256, 4, bm, bn);
  f32x4 acc[8][4];
  gemm256b(A, Bm, Mm, bm, bn, Al, Bl, acc);

  const int lane = threadIdx.x & 63, w = threadIdx.x >> 6;
  const int wm = w >> 2, wn = w & 3;
  const int qi = lane & 15, g = lane >> 4;
  const int cb = bn * 256 + wn * 64;         // 64-aligned -> single (proj, head)
  const int proj = cb / Cc;
  const int within = cb - proj * Cc;
  const float* bias = proj == 0 ? bq : proj == 1 ? bk : bv;
  short* dst = proj == 0 ? qv : proj == 1 ? kv : vv;
  const float sc = proj == 0 ? QSCALE : 1.0f;
  const int hh = within >> 6;
  float bvv[4];
#pragma unroll
  for (int n = 0; n < 4; ++n) bvv[n] = bias[within + n * 16 + qi];
#pragma unroll
  for (int m = 0; m < 8; ++m)
#pragma unroll
    for (int r = 0; r < 4; ++r) {
      int row = bm * 256 + wm * 128 + m * 16 + g * 4 + r;
      if (row < Mm) {
        int b = row / Nn;
        int nn = row - b * Nn;
        size_t base = ((size_t)(b * Hh + hh) * Nn + nn) * DK;
#pragma unroll
        for (int n = 0; n < 4; ++n)
          dst[base + n * 16 + qi] = f2bf((acc[m][n][r] + bvv[n]) * sc);
      }
    }
}

// GEMM2: attn_out_bf16 @ Wo^T + bo -> fp32 out [M][768]
__global__ __launch_bounds__(512) void k_gemm_out(
    const short* __restrict__ A, const short* __restrict__ Bm,
    const float* __restrict__ bo, float* __restrict__ out) {
  __shared__ short Al[2 * 16384];
  __shared__ short Bl[2 * 16384];
  int bm, bn;
  remap_grouped((int)blockIdx.x, (Mm + 255) / 256, Cc / 256, 8, bm, bn);
  f32x4 acc[8][4];
  gemm256b(A, Bm, Mm, bm, bn, Al, Bl, acc);

  const int lane = threadIdx.x & 63, w = threadIdx.x >> 6;
  const int wm = w >> 2, wn = w & 3;
  const int qi = lane & 15, g = lane >> 4;
  const int cb = bn * 256 + wn * 64;
  float bvv[4];
#pragma unroll
  for (int n = 0; n < 4; ++n) bvv[n] = bo[cb + n * 16 + qi];
#pragma unroll
  for (int m = 0; m < 8; ++m)
#pragma unroll
    for (int r = 0; r < 4; ++r) {
      int row = bm * 256 + wm * 128 + m * 16 + g * 4 + r;
      if (row < Mm) {
#pragma unroll
        for (int n = 0; n < 4; ++n)
          out[(size_t)row * Cc + cb + n * 16 + qi] = acc[m][n][r] + bvv[n];
      }
    }
}

// V transpose: v [B,H,577,64] -> vt [B,H,64,640], zero-padded keys 577..639
__global__ __launch_bounds__(256) void k_transpose_v(const short* __restrict__ v,
                                                     short* __restrict__ vt) {
  __shared__ short t[64 * 72];
  const int bid = blockIdx.x;
  const int ch = bid % NT, bh = bid / NT;
  const int tid = threadIdx.x;
  const short* vb = v + (size_t)bh * Nn * DK;
#pragma unroll
  for (int i = 0; i < 2; ++i) {
    int gi = i * 256 + tid;
    int r = gi >> 3, c = gi & 7;
    int n = ch * 64 + r;
    short8 val;
#pragma unroll
    for (int j = 0; j < 8; ++j) val[j] = 0;
    if (n < Nn) val = *(const short8*)(vb + (size_t)n * DK + c * 8);
    *(short8*)(t + r * 72 + c * 8) = val;
  }
  __syncthreads();
  short* ob = vt + (size_t)bh * DK * NKPAD + ch * 64;
#pragma unroll
  for (int i = 0; i < 2; ++i) {
    int gi = i * 256 + tid;
    int d = gi >> 3, cg = gi & 7;
    short8 o;
#pragma unroll
    for (int j = 0; j < 8; ++j) o[j] = t[(cg * 8 + j) * 72 + d];
    *(short8*)(ob + (size_t)d * NKPAD + cg * 8) = o;
  }
}

// Flash attention: swapped-QK^T, no-max softmax, 2 q-tiles/block with
// (a) K/V fragments read from LDS ONCE per tile (register-shared across both
// q-tiles) and (b) ONE shared P buffer (40KB LDS -> 4 blocks/CU). No
// min-waves clause (R9 spill lesson). Unchanged from R11.
__global__ __launch_bounds__(256) void k_attn(const short* __restrict__ q,
                                              const short* __restrict__ k,
                                              const short* __restrict__ vt,
                                              short* __restrict__ ao) {
  __shared__ short Ks[2][64 * 64];
  __shared__ short Vs[2][64 * 64];
  __shared__ short Ps[4][16 * 64];     // per-wave, shared by both q-tiles
  int bid = (int)blockIdx.x;
  bid = (bid & 7) * 240 + (bid >> 3);  // XCD swizzle: 1920 = 8*240, bijective
  const int qtp = bid % 5, bh = bid / 5;
  const int qt0 = qtp * 2;
  const int bb = bh / Hh, hh = bh - bb * Hh;
  const int tid = threadIdx.x, lane = tid & 63, w = tid >> 6;
  const int qi = lane & 15, g = lane >> 4;

  const short* qb  = q  + (size_t)bh * Nn * DK;
  const short* kb  = k  + (size_t)bh * Nn * DK;
  const short* vtb = vt + (size_t)bh * DK * NKPAD;

  const int qrow = qt0 * 64 + w * 16 + qi;
  const bf16x8 qf0a = *(const bf16x8*)(qb + (size_t)qrow * DK + g * 8);
  const bf16x8 qf1a = *(const bf16x8*)(qb + (size_t)qrow * DK + 32 + g * 8);
  const bf16x8 qf0b = *(const bf16x8*)(qb + (size_t)(qrow + 64) * DK + g * 8);
  const bf16x8 qf1b = *(const bf16x8*)(qb + (size_t)(qrow + 64) * DK + 32 + g * 8);

  const int r0 = tid >> 3, cc = tid & 7;
  const int cs0 = (cc ^ (r0 & 7)) * 8;
  const short* kg = kb + r0 * DK + cs0;
  const short* vg = vtb + (size_t)r0 * NKPAD + cs0;
  short* const Kd0 = &Ks[0][w * 512]; short* const Kd1 = &Ks[1][w * 512];
  short* const Vd0 = &Vs[0][w * 512]; short* const Vd1 = &Vs[1][w * 512];

  auto stage = [&](short* Kd, short* Vd) {
    gload16(kg, Kd);          gload16(kg + 2048,  Kd + 2048);
    gload16(vg, Vd);          gload16(vg + 20480, Vd + 2048);
    kg += 4096;               vg += 64;
  };

  const int swq = qi & 7;
  const short* const KF00 = &Ks[0][qi * 64 + ((g    ) ^ swq) * 8];
  const short* const KF01 = &Ks[0][qi * 64 + ((g + 4) ^ swq) * 8];
  const short* const KF10 = &Ks[1][qi * 64 + ((g    ) ^ swq) * 8];
  const short* const KF11 = &Ks[1][qi * 64 + ((g + 4) ^ swq) * 8];
  const short* const VF00 = &Vs[0][qi * 64 + ((g    ) ^ swq) * 8];
  const short* const VF01 = &Vs[0][qi * 64 + ((g + 4) ^ swq) * 8];
  const short* const VF10 = &Vs[1][qi * 64 + ((g    ) ^ swq) * 8];
  const short* const VF11 = &Vs[1][qi * 64 + ((g + 4) ^ swq) * 8];
  short* const PW0 = &Ps[w][qi * 64 + (((0  + g) ^ (swq << 1)) << 2)];
  short* const PW1 = &Ps[w][qi * 64 + (((4  + g) ^ (swq << 1)) << 2)];
  short* const PW2 = &Ps[w][qi * 64 + (((8  + g) ^ (swq << 1)) << 2)];
  short* const PW3 = &Ps[w][qi * 64 + (((12 + g) ^ (swq << 1)) << 2)];
  const short* const PR0 = &Ps[w][qi * 64 + ((g    ) ^ swq) * 8];
  const short* const PR1 = &Ps[w][qi * 64 + ((g + 4) ^ swq) * 8];

  f32x4 accA[4], accB[4];
#pragma unroll
  for (int nd = 0; nd < 4; ++nd) { accA[nd] = (f32x4)0.0f; accB[nd] = (f32x4)0.0f; }
  float lsA = 0.f, lsB = 0.f;

  auto smax = [&](f32x4* s, float& ls, bool last) {
    if (last) {                        // keys 577..639 invalid
#pragma unroll
      for (int ni = 0; ni < 4; ++ni)
#pragma unroll
        for (int r = 0; r < 4; ++r)
          if (ni || r) s[ni][r] = -1e30f;
      if (g) s[0][0] = -1e30f;
    }
    float rs = 0.f;
    short4v pk0, pk1, pk2, pk3;
#pragma unroll
    for (int r = 0; r < 4; ++r) { float p = exp2f(s[0][r]); rs += p; pk0[r] = f2bf(p); }
#pragma unroll
    for (int r = 0; r < 4; ++r) { float p = exp2f(s[1][r]); rs += p; pk1[r] = f2bf(p); }
#pragma unroll
    for (int r = 0; r < 4; ++r) { float p = exp2f(s[2][r]); rs += p; pk2[r] = f2bf(p); }
#pragma unroll
    for (int r = 0; r < 4; ++r) { float p = exp2f(s[3][r]); rs += p; pk3[r] = f2bf(p); }
    *(short4v*)PW0 = pk0; *(short4v*)PW1 = pk1;
    *(short4v*)PW2 = pk2; *(short4v*)PW3 = pk3;
    rs += __shfl_xor(rs, 16);
    rs += __shfl_xor(rs, 32);
    ls += rs;
  };

  auto tilestep = [&](const short* Kf0, const short* Kf1,
                      const short* Vf0, const short* Vf1, bool last) {
    f32x4 sA[4], sB[4];
#pragma unroll
    for (int ni = 0; ni < 4; ++ni) { sA[ni] = (f32x4)0.0f; sB[ni] = (f32x4)0.0f; }
    {
      bf16x8 kf[4];
#pragma unroll
      for (int ni = 0; ni < 4; ++ni) kf[ni] = *(const bf16x8*)(Kf0 + ni * 1024);
#pragma unroll
      for (int ni = 0; ni < 4; ++ni) sA[ni] = mfma16(kf[ni], qf0a, sA[ni]);
#pragma unroll
      for (int ni = 0; ni < 4; ++ni) sB[ni] = mfma16(kf[ni], qf0b, sB[ni]);
#pragma unroll
      for (int ni = 0; ni < 4; ++ni) kf[ni] = *(const bf16x8*)(Kf1 + ni * 1024);
#pragma unroll
      for (int ni = 0; ni < 4; ++ni) sA[ni] = mfma16(kf[ni], qf1a, sA[ni]);
#pragma unroll
      for (int ni = 0; ni < 4; ++ni) sB[ni] = mfma16(kf[ni], qf1b, sB[ni]);
    }
    smax(sA, lsA, last);
    bf16x8 paA0 = *(const bf16x8*)PR0;   // reads issued before P is overwritten
    bf16x8 paA1 = *(const bf16x8*)PR1;
    smax(sB, lsB, last);
    bf16x8 paB0 = *(const bf16x8*)PR0;
    bf16x8 paB1 = *(const bf16x8*)PR1;
    {
      bf16x8 vf[4];
#pragma unroll
      for (int nd = 0; nd < 4; ++nd) vf[nd] = *(const bf16x8*)(Vf0 + nd * 1024);
#pragma unroll
      for (int nd = 0; nd < 4; ++nd) accA[nd] = mfma16(paA0, vf[nd], accA[nd]);
#pragma unroll
      for (int nd = 0; nd < 4; ++nd) accB[nd] = mfma16(paB0, vf[nd], accB[nd]);
#pragma unroll
      for (int nd = 0; nd < 4; ++nd) vf[nd] = *(const bf16x8*)(Vf1 + nd * 1024);
#pragma unroll
      for (int nd = 0; nd < 4; ++nd) accA[nd] = mfma16(paA1, vf[nd], accA[nd]);
#pragma unroll
      for (int nd = 0; nd < 4; ++nd) accB[nd] = mfma16(paB1, vf[nd], accB[nd]);
    }
  };

  stage(Kd0, Vd0);
  __syncthreads();
#pragma unroll 1
  for (int t2 = 0; t2 < 5; ++t2) {
    stage(Kd1, Vd1);
    tilestep(KF00, KF01, VF00, VF01, false);
    __syncthreads();
    if (t2 < 4) {
      stage(Kd0, Vd0);
      tilestep(KF10, KF11, VF10, VF11, false);
      __syncthreads();
    }
  }
  tilestep(KF10, KF11, VF10, VF11, true);

  auto epi = [&](f32x4* accd, float ls, int qt) {
    float ls4[4];
#pragma unroll
    for (int r = 0; r < 4; ++r) ls4[r] = __shfl(ls, (g << 2) + r);
#pragma unroll
    for (int r = 0; r < 4; ++r) {
      int qr = qt * 64 + w * 16 + (g << 2) + r;
      if (qr < Nn) {
        float inv = 1.0f / ls4[r];
        size_t base = ((size_t)(bb * Nn + qr)) * Cc + hh * DK;
#pragma unroll
        for (int nd = 0; nd < 4; ++nd)
          ao[base + nd * 16 + qi] = f2bf(accd[nd][r] * inv);
      }
    }
  };
  epi(accA, lsA, qt0);
  epi(accB, lsB, qt0 + 1);
}

// ---------------- launch ----------------

extern "C" void kernel_launch(void* const* d_in, const int* in_sizes, int n_in,
                              void* d_out, int out_size, void* d_ws, size_t ws_size,
                              hipStream_t stream) {
  const float* x  = (const float*)d_in[0];
  const float* Wq = (const float*)d_in[1];
  const float* bq = (const float*)d_in[2];
  const float* Wk = (const float*)d_in[3];
  const float* bk = (const float*)d_in[4];
  const float* Wv = (const float*)d_in[5];
  const float* bv = (const float*)d_in[6];
  const float* Wo = (const float*)d_in[7];
  const float* bo = (const float*)d_in[8];
  float* out = (float*)d_out;

  char* ws = (char*)d_ws;
  size_t off = 0;
  auto alloc = [&](size_t bytes) {
    char* p = ws + off;
    off += (bytes + 255) & ~(size_t)255;
    return p;
  };
  short* xb   = (short*)alloc((size_t)Mm * Cc * 2);          // x bf16 (reused as attn_out)
  short* wqkv = (short*)alloc((size_t)NQKV * Cc * 2);
  short* wob  = (short*)alloc((size_t)Cc * Cc * 2);
  short* qb   = (short*)alloc((size_t)Bb * Hh * Nn * DK * 2);
  short* kb   = (short*)alloc((size_t)Bb * Hh * Nn * DK * 2);
  short* vb   = (short*)alloc((size_t)Bb * Hh * Nn * DK * 2);
  short* vtb  = (short*)alloc((size_t)Bb * Hh * DK * NKPAD * 2);
  short* aob  = xb;   // x_bf16 dead after GEMM1; alias for attn output

  const int NCVT = Mm * Cc / 4 + Cc * Cc;    // x float4s + 4 weight matrices
  k_cvt_all<<<(NCVT + 255) / 256, 256, 0, stream>>>(x, Wq, Wk, Wv, Wo, xb, wqkv, wob);

  const int nbm = (Mm + 255) / 256;        // 73
  k_gemm_qkv<<<nbm * (NQKV / 256), 512, 0, stream>>>(xb, wqkv, bq, bk, bv, qb, kb, vb);

  k_transpose_v<<<Bb * Hh * NT, 256, 0, stream>>>(vb, vtb);

  k_attn<<<Bb * Hh * 5, 256, 0, stream>>>(qb, kb, vtb, aob);

  k_gemm_out<<<nbm * (Cc / 256), 512, 0, stream>>>(aob, wob, bo, out);
}

// Round 14
// 199.705 us; speedup vs baseline: 1.1028x; 1.0642x over previous
//
#include <hip/hip_runtime.h>
#include <cstdint>
#include <cstddef>

typedef float  f32x4   __attribute__((ext_vector_type(4)));
typedef __bf16 bf16x8  __attribute__((ext_vector_type(8)));
typedef short  short8  __attribute__((ext_vector_type(8)));
typedef short  short4v __attribute__((ext_vector_type(4)));
typedef float  float4v __attribute__((ext_vector_type(4)));

#define DEVI __device__ __forceinline__

constexpr int Bb = 32, Nn = 577, Cc = 768, Hh = 12, DK = 64;
constexpr int Mm   = Bb * Nn;     // 18464 rows
constexpr int NQKV = 3 * Cc;      // 2304 fused QKV output cols
constexpr int NKPAD = 640;        // padded key count (10 tiles of 64)
constexpr int NT = 10;
#define QSCALE 0.1803368926f      // 0.125 * log2(e) folded into Q

DEVI short f2bf(float f) {
  __bf16 h = (__bf16)f;
  short s;
  __builtin_memcpy(&s, &h, 2);
  return s;
}

DEVI float fexp2(float x) { return __builtin_amdgcn_exp2f(x); }  // bare v_exp_f32

DEVI void gload16(const short* g, short* l) {   // async global->LDS, 16B/lane
  __builtin_amdgcn_global_load_lds(
      (const __attribute__((address_space(1))) void*)g,
      (__attribute__((address_space(3))) void*)l, 16, 0, 0);
}

DEVI f32x4 mfma16(bf16x8 a, bf16x8 b, f32x4 c) {
  return __builtin_amdgcn_mfma_f32_16x16x32_bf16(a, b, c, 0, 0, 0);
}

// XCD-bijective chunking over Triton-style grouped ordering.
DEVI void remap_grouped(int bid, int nbm, int nbn, int GM, int& bm, int& bn) {
  const int nwg = nbm * nbn;
  const int xcd = bid & 7, j = bid >> 3;
  const int q = nwg >> 3, r = nwg & 7;
  int wg = (xcd < r ? xcd * (q + 1) : r * (q + 1) + (xcd - r) * q) + j;
  const int per = GM * nbn;
  int grp = wg / per;
  int first = grp * GM;
  int sz = min(GM, nbm - first);
  int rem = wg - grp * per;
  bm = first + rem % sz;
  bn = rem / sz;
}

// ---------------- single fused conversion kernel (grid-stride, G11) ----------

__global__ void k_cvt_all(const float* __restrict__ x,
                          const float* __restrict__ Wq, const float* __restrict__ Wk,
                          const float* __restrict__ Wv, const float* __restrict__ Wo,
                          short* __restrict__ xb, short* __restrict__ wqkv,
                          short* __restrict__ wob) {
  const int NX4   = Mm * Cc / 4;        // float4s of x
  const int WSZ4  = Cc * Cc / 4;        // per weight matrix
  const int NTOT  = NX4 + 4 * WSZ4;
  for (int i = blockIdx.x * 256 + threadIdx.x; i < NTOT; i += gridDim.x * 256) {
    const float* src;
    short* dst;
    int e;
    if (i < NX4) { src = x; dst = xb; e = i; }
    else {
      int j = i - NX4;
      if (j < WSZ4)          { src = Wq; dst = wqkv;                e = j; }
      else if (j < 2 * WSZ4) { src = Wk; dst = wqkv + WSZ4 * 4;     e = j - WSZ4; }
      else if (j < 3 * WSZ4) { src = Wv; dst = wqkv + 2 * WSZ4 * 4; e = j - 2 * WSZ4; }
      else                   { src = Wo; dst = wob;                 e = j - 3 * WSZ4; }
    }
    float4v v = *(const float4v*)(src + (size_t)e * 4);
    short4v o;
#pragma unroll
    for (int t = 0; t < 4; ++t) o[t] = f2bf(v[t]);
    *(short4v*)(dst + (size_t)e * 4) = o;
  }
}

#define WAITV(N) asm volatile("s_waitcnt vmcnt(" #N ")" ::: "memory")

// ============ core B: [256][64]-row tiles, 8-granule XOR (0-conflict), 8-phase
// schedule (R11/R13-validated best; R12's merged 4-phase regressed).
#define GPH(BUF, KK, MH, STAGE, WAIT)                                      \
  {                                                                        \
    const short* Ab_ = Al + (BUF) * 16384;                                 \
    const short* Bb_ = Bl + (BUF) * 16384;                                 \
    bf16x8 af_[4];                                                         \
    _Pragma("unroll")                                                      \
    for (int m_ = 0; m_ < 4; ++m_)                                         \
      af_[m_] = *(const bf16x8*)(Ab_ + (offA[(MH) * 4 + m_] ^ ((KK) * 32))); \
    if ((MH) == 0) {                                                       \
      _Pragma("unroll")                                                    \
      for (int n_ = 0; n_ < 4; ++n_)                                       \
        bfr[n_] = *(const bf16x8*)(Bb_ + (offB[n_] ^ ((KK) * 32)));        \
    }                                                                      \
    STAGE;                                                                 \
    WAIT;                                                                  \
    __builtin_amdgcn_s_barrier();                                          \
    __builtin_amdgcn_s_setprio(1);                                         \
    _Pragma("unroll")                                                      \
    for (int m_ = 0; m_ < 4; ++m_)                                         \
      _Pragma("unroll")                                                    \
      for (int n_ = 0; n_ < 4; ++n_)                                       \
        acc[(MH) * 4 + m_][n_] = mfma16(af_[m_], bfr[n_], acc[(MH) * 4 + m_][n_]); \
    __builtin_amdgcn_s_setprio(0);                                         \
    __builtin_amdgcn_s_barrier();                                          \
  }

DEVI void gemm256b(const short* __restrict__ A, const short* __restrict__ Bm,
                   int arows, int bm, int bn,
                   short* Al, short* Bl, f32x4 acc[8][4]) {
  const int tid = threadIdx.x;               // 0..511
  const int lane = tid & 63, w = tid >> 6;
  const int wm = w >> 2, wn = w & 3;
  const int qi = lane & 15, g = lane >> 4;

#pragma unroll
  for (int m = 0; m < 8; ++m)
#pragma unroll
    for (int n = 0; n < 4; ++n) acc[m][n] = (f32x4)0.0f;

  const int rloc = tid >> 3, c8 = tid & 7;
  const int gswz = (c8 ^ (rloc & 7)) * 8;
  const short* pA[4];
  const short* pB[4];
#pragma unroll
  for (int s = 0; s < 4; ++s) {
    int ra = bm * 256 + s * 64 + rloc; if (ra > arows - 1) ra = arows - 1;
    pA[s] = A  + (size_t)ra * Cc + gswz;
    pB[s] = Bm + (size_t)(bn * 256 + s * 64 + rloc) * Cc + gswz;
  }
  auto stA = [&](int buf, int s, int co) {
    gload16(pA[s] + co, Al + buf * 16384 + s * 4096 + tid * 8);
  };
  auto stB = [&](int buf, int s, int co) {
    gload16(pB[s] + co, Bl + buf * 16384 + s * 4096 + tid * 8);
  };

  int offA[8], offB[4];
#pragma unroll
  for (int m = 0; m < 8; ++m) {
    int r = wm * 128 + m * 16 + qi;
    offA[m] = r * 64 + ((g ^ (r & 7)) * 8);
  }
#pragma unroll
  for (int n = 0; n < 4; ++n) {
    int r = wn * 64 + n * 16 + qi;
    offB[n] = r * 64 + ((g ^ (r & 7)) * 8);
  }
  bf16x8 bfr[4];

  // prologue: tile0 A+B (8 segs), tile1 B{0,1}; WAITV(2) -> tile0 resident
  stA(0, 0, 0); stA(0, 1, 0); stA(0, 2, 0); stA(0, 3, 0);
  stB(0, 0, 0); stB(0, 1, 0); stB(0, 2, 0); stB(0, 3, 0);
  stB(1, 0, 64); stB(1, 1, 64);
  WAITV(2);
  __builtin_amdgcn_s_barrier();

#pragma unroll 1
  for (int i = 0; i < 5; ++i) {
    const int cb1  = 64 + 128 * i;     // tile 2i+1 cols
    const int cb0n = cb1 + 64;         // tile 2i+2
    const int cb1n = cb1 + 128;        // tile 2i+3
    GPH(0, 0, 0, (stB(1, 2, cb1),  stB(1, 3, cb1)),  (void)0);
    GPH(0, 0, 1, (stA(1, 0, cb1),  stA(1, 2, cb1)),  (void)0);
    GPH(0, 1, 0, (stA(1, 1, cb1),  stA(1, 3, cb1)),  (void)0);
    GPH(0, 1, 1, (stA(0, 0, cb0n), stA(0, 2, cb0n)), WAITV(4));
    GPH(1, 0, 0, (stA(0, 1, cb0n), stA(0, 3, cb0n)), WAITV(4));
    GPH(1, 0, 1, (stB(0, 0, cb0n), stB(0, 1, cb0n)), (void)0);
    GPH(1, 1, 0, (stB(0, 2, cb0n), stB(0, 3, cb0n)), (void)0);
    GPH(1, 1, 1, (stB(1, 0, cb1n), stB(1, 1, cb1n)), WAITV(2));
  }
  // tail: tiles 10 (buf0), 11 (buf1); finish staging tile 11 (col 704)
  GPH(0, 0, 0, (stB(1, 2, 704), stB(1, 3, 704)), (void)0);
  GPH(0, 0, 1, (stA(1, 0, 704), stA(1, 2, 704)), (void)0);
  GPH(0, 1, 0, (stA(1, 1, 704), stA(1, 3, 704)), (void)0);
  GPH(0, 1, 1, (void)0, WAITV(2));
  GPH(1, 0, 0, (void)0, WAITV(0));
  GPH(1, 0, 1, (void)0, (void)0);
  GPH(1, 1, 0, (void)0, (void)0);
  GPH(1, 1, 1, (void)0, (void)0);
}

// GEMM1: x_bf16 @ [Wq;Wk;Wv]^T + b -> q/k/v [B,H,N,64] bf16 (Q scaled).
__global__ __launch_bounds__(512) void k_gemm_qkv(
    const short* __restrict__ A, const short* __restrict__ Bm,
    const float* __restrict__ bq, const float* __restrict__ bk, const float* __restrict__ bv,
    short* __restrict__ qv, short* __restrict__ kv, short* __restrict__ vv) {
  __shared__ short Al[2 * 16384];
  __shared__ short Bl[2 * 16384];
  int bm, bn;
  remap_grouped((int)blockIdx.x, (Mm + 255) / 256, NQKV / 256, 4, bm, bn);
  f32x4 acc[8][4];
  gemm256b(A, Bm, Mm, bm, bn, Al, Bl, acc);

  const int lane = threadIdx.x & 63, w = threadIdx.x >> 6;
  const int wm = w >> 2, wn = w & 3;
  const int qi = lane & 15, g = lane >> 4;
  const int cb = bn * 256 + wn * 64;         // 64-aligned -> single (proj, head)
  const int proj = cb / Cc;
  const int within = cb - proj * Cc;
  const float* bias = proj == 0 ? bq : proj == 1 ? bk : bv;
  short* dst = proj == 0 ? qv : proj == 1 ? kv : vv;
  const float sc = proj == 0 ? QSCALE : 1.0f;
  const int hh = within >> 6;
  float bvv[4];
#pragma unroll
  for (int n = 0; n < 4; ++n) bvv[n] = bias[within + n * 16 + qi];
#pragma unroll
  for (int m = 0; m < 8; ++m)
#pragma unroll
    for (int r = 0; r < 4; ++r) {
      int row = bm * 256 + wm * 128 + m * 16 + g * 4 + r;
      if (row < Mm) {
        int b = row / Nn;
        int nn = row - b * Nn;
        size_t base = ((size_t)(b * Hh + hh) * Nn + nn) * DK;
#pragma unroll
        for (int n = 0; n < 4; ++n)
          dst[base + n * 16 + qi] = f2bf((acc[m][n][r] + bvv[n]) * sc);
      }
    }
}

// GEMM2: attn_out_bf16 @ Wo^T + bo -> fp32 out [M][768]
__global__ __launch_bounds__(512) void k_gemm_out(
    const short* __restrict__ A, const short* __restrict__ Bm,
    const float* __restrict__ bo, float* __restrict__ out) {
  __shared__ short Al[2 * 16384];
  __shared__ short Bl[2 * 16384];
  int bm, bn;
  remap_grouped((int)blockIdx.x, (Mm + 255) / 256, Cc / 256, 8, bm, bn);
  f32x4 acc[8][4];
  gemm256b(A, Bm, Mm, bm, bn, Al, Bl, acc);

  const int lane = threadIdx.x & 63, w = threadIdx.x >> 6;
  const int wm = w >> 2, wn = w & 3;
  const int qi = lane & 15, g = lane >> 4;
  const int cb = bn * 256 + wn * 64;
  float bvv[4];
#pragma unroll
  for (int n = 0; n < 4; ++n) bvv[n] = bo[cb + n * 16 + qi];
#pragma unroll
  for (int m = 0; m < 8; ++m)
#pragma unroll
    for (int r = 0; r < 4; ++r) {
      int row = bm * 256 + wm * 128 + m * 16 + g * 4 + r;
      if (row < Mm) {
#pragma unroll
        for (int n = 0; n < 4; ++n)
          out[(size_t)row * Cc + cb + n * 16 + qi] = acc[m][n][r] + bvv[n];
      }
    }
}

// V transpose: v [B,H,577,64] -> vt [B,H,64,640], zero-padded keys 577..639
__global__ __launch_bounds__(256) void k_transpose_v(const short* __restrict__ v,
                                                     short* __restrict__ vt) {
  __shared__ short t[64 * 72];
  const int bid = blockIdx.x;
  const int ch = bid % NT, bh = bid / NT;
  const int tid = threadIdx.x;
  const short* vb = v + (size_t)bh * Nn * DK;
#pragma unroll
  for (int i = 0; i < 2; ++i) {
    int gi = i * 256 + tid;
    int r = gi >> 3, c = gi & 7;
    int n = ch * 64 + r;
    short8 val;
#pragma unroll
    for (int j = 0; j < 8; ++j) val[j] = 0;
    if (n < Nn) val = *(const short8*)(vb + (size_t)n * DK + c * 8);
    *(short8*)(t + r * 72 + c * 8) = val;
  }
  __syncthreads();
  short* ob = vt + (size_t)bh * DK * NKPAD + ch * 64;
#pragma unroll
  for (int i = 0; i < 2; ++i) {
    int gi = i * 256 + tid;
    int d = gi >> 3, cg = gi & 7;
    short8 o;
#pragma unroll
    for (int j = 0; j < 8; ++j) o[j] = t[(cg * 8 + j) * 72 + d];
    *(short8*)(ob + (size_t)d * NKPAD + cg * 8) = o;
  }
}

// Flash attention: swapped-QK^T, no-max softmax, 2 q-tiles/block, K/V frags
// register-shared across q-tiles, ONE shared P buffer (40KB LDS). Last key
// tile (1 valid key of 64) runs a specialized cheap path: 6 MFMA vs 16/q-tile.
__global__ __launch_bounds__(256) void k_attn(const short* __restrict__ q,
                                              const short* __restrict__ k,
                                              const short* __restrict__ vt,
                                              short* __restrict__ ao) {
  __shared__ short Ks[2][64 * 64];
  __shared__ short Vs[2][64 * 64];
  __shared__ short Ps[4][16 * 64];     // per-wave, shared by both q-tiles
  int bid = (int)blockIdx.x;
  bid = (bid & 7) * 240 + (bid >> 3);  // XCD swizzle: 1920 = 8*240, bijective
  const int qtp = bid % 5, bh = bid / 5;
  const int qt0 = qtp * 2;
  const int bb = bh / Hh, hh = bh - bb * Hh;
  const int tid = threadIdx.x, lane = tid & 63, w = tid >> 6;
  const int qi = lane & 15, g = lane >> 4;

  const short* qb  = q  + (size_t)bh * Nn * DK;
  const short* kb  = k  + (size_t)bh * Nn * DK;
  const short* vtb = vt + (size_t)bh * DK * NKPAD;

  const int qrow = qt0 * 64 + w * 16 + qi;
  const bf16x8 qf0a = *(const bf16x8*)(qb + (size_t)qrow * DK + g * 8);
  const bf16x8 qf1a = *(const bf16x8*)(qb + (size_t)qrow * DK + 32 + g * 8);
  const bf16x8 qf0b = *(const bf16x8*)(qb + (size_t)(qrow + 64) * DK + g * 8);
  const bf16x8 qf1b = *(const bf16x8*)(qb + (size_t)(qrow + 64) * DK + 32 + g * 8);

  const int r0 = tid >> 3, cc = tid & 7;
  const int cs0 = (cc ^ (r0 & 7)) * 8;
  const short* kg = kb + r0 * DK + cs0;
  const short* vg = vtb + (size_t)r0 * NKPAD + cs0;
  short* const Kd0 = &Ks[0][w * 512]; short* const Kd1 = &Ks[1][w * 512];
  short* const Vd0 = &Vs[0][w * 512]; short* const Vd1 = &Vs[1][w * 512];

  auto stage = [&](short* Kd, short* Vd) {
    gload16(kg, Kd);          gload16(kg + 2048,  Kd + 2048);
    gload16(vg, Vd);          gload16(vg + 20480, Vd + 2048);
    kg += 4096;               vg += 64;
  };

  const int swq = qi & 7;
  const short* const KF00 = &Ks[0][qi * 64 + ((g    ) ^ swq) * 8];
  const short* const KF01 = &Ks[0][qi * 64 + ((g + 4) ^ swq) * 8];
  const short* const KF10 = &Ks[1][qi * 64 + ((g    ) ^ swq) * 8];
  const short* const KF11 = &Ks[1][qi * 64 + ((g + 4) ^ swq) * 8];
  const short* const VF00 = &Vs[0][qi * 64 + ((g    ) ^ swq) * 8];
  const short* const VF01 = &Vs[0][qi * 64 + ((g + 4) ^ swq) * 8];
  const short* const VF10 = &Vs[1][qi * 64 + ((g    ) ^ swq) * 8];
  const short* const VF11 = &Vs[1][qi * 64 + ((g + 4) ^ swq) * 8];
  short* const PW0 = &Ps[w][qi * 64 + (((0  + g) ^ (swq << 1)) << 2)];
  short* const PW1 = &Ps[w][qi * 64 + (((4  + g) ^ (swq << 1)) << 2)];
  short* const PW2 = &Ps[w][qi * 64 + (((8  + g) ^ (swq << 1)) << 2)];
  short* const PW3 = &Ps[w][qi * 64 + (((12 + g) ^ (swq << 1)) << 2)];
  const short* const PR0 = &Ps[w][qi * 64 + ((g    ) ^ swq) * 8];
  const short* const PR1 = &Ps[w][qi * 64 + ((g + 4) ^ swq) * 8];

  f32x4 accA[4], accB[4];
#pragma unroll
  for (int nd = 0; nd < 4; ++nd) { accA[nd] = (f32x4)0.0f; accB[nd] = (f32x4)0.0f; }
  float lsA = 0.f, lsB = 0.f;

  auto smax = [&](f32x4* s, float& ls) {
    float rs = 0.f;
    short4v pk0, pk1, pk2, pk3;
#pragma unroll
    for (int r = 0; r < 4; ++r) { float p = fexp2(s[0][r]); rs += p; pk0[r] = f2bf(p); }
#pragma unroll
    for (int r = 0; r < 4; ++r) { float p = fexp2(s[1][r]); rs += p; pk1[r] = f2bf(p); }
#pragma unroll
    for (int r = 0; r < 4; ++r) { float p = fexp2(s[2][r]); rs += p; pk2[r] = f2bf(p); }
#pragma unroll
    for (int r = 0; r < 4; ++r) { float p = fexp2(s[3][r]); rs += p; pk3[r] = f2bf(p); }
    *(short4v*)PW0 = pk0; *(short4v*)PW1 = pk1;
    *(short4v*)PW2 = pk2; *(short4v*)PW3 = pk3;
    rs += __shfl_xor(rs, 16);
    rs += __shfl_xor(rs, 32);
    ls += rs;
  };

  auto tilestep = [&](const short* Kf0, const short* Kf1,
                      const short* Vf0, const short* Vf1) {
    f32x4 sA[4], sB[4];
#pragma unroll
    for (int ni = 0; ni < 4; ++ni) { sA[ni] = (f32x4)0.0f; sB[ni] = (f32x4)0.0f; }
    {
      bf16x8 kf[4];
#pragma unroll
      for (int ni = 0; ni < 4; ++ni) kf[ni] = *(const bf16x8*)(Kf0 + ni * 1024);
#pragma unroll
      for (int ni = 0; ni < 4; ++ni) sA[ni] = mfma16(kf[ni], qf0a, sA[ni]);
#pragma unroll
      for (int ni = 0; ni < 4; ++ni) sB[ni] = mfma16(kf[ni], qf0b, sB[ni]);
#pragma unroll
      for (int ni = 0; ni < 4; ++ni) kf[ni] = *(const bf16x8*)(Kf1 + ni * 1024);
#pragma unroll
      for (int ni = 0; ni < 4; ++ni) sA[ni] = mfma16(kf[ni], qf1a, sA[ni]);
#pragma unroll
      for (int ni = 0; ni < 4; ++ni) sB[ni] = mfma16(kf[ni], qf1b, sB[ni]);
    }
    smax(sA, lsA);
    bf16x8 paA0 = *(const bf16x8*)PR0;   // reads issued before P is overwritten
    bf16x8 paA1 = *(const bf16x8*)PR1;
    smax(sB, lsB);
    bf16x8 paB0 = *(const bf16x8*)PR0;
    bf16x8 paB1 = *(const bf16x8*)PR1;
    {
      bf16x8 vf[4];
#pragma unroll
      for (int nd = 0; nd < 4; ++nd) vf[nd] = *(const bf16x8*)(Vf0 + nd * 1024);
#pragma unroll
      for (int nd = 0; nd < 4; ++nd) accA[nd] = mfma16(paA0, vf[nd], accA[nd]);
#pragma unroll
      for (int nd = 0; nd < 4; ++nd) accB[nd] = mfma16(paB0, vf[nd], accB[nd]);
#pragma unroll
      for (int nd = 0; nd < 4; ++nd) vf[nd] = *(const bf16x8*)(Vf1 + nd * 1024);
#pragma unroll
      for (int nd = 0; nd < 4; ++nd) accA[nd] = mfma16(paA1, vf[nd], accA[nd]);
#pragma unroll
      for (int nd = 0; nd < 4; ++nd) accB[nd] = mfma16(paB1, vf[nd], accB[nd]);
    }
  };

  // Specialized last tile: only key 576 (tile-local 0) valid. QK: ni=0 only
  // (2 MFMA/q-tile); P: pk0 masked (g==0,r==0), pk1=0; PV: kk=0 only (keys
  // 0..31 of tile; pa1's keys all invalid -> skipped entirely).
  auto lasttile = [&](const short* Kf0, const short* Kf1,
                      const short* Vf0) {
    auto one = [&](const bf16x8& qf0, const bf16x8& qf1, f32x4* accd, float& ls) {
      f32x4 s0 = (f32x4)0.0f;
      s0 = mfma16(*(const bf16x8*)(Kf0), qf0, s0);
      s0 = mfma16(*(const bf16x8*)(Kf1), qf1, s0);
      float rs = 0.f;
      short4v pk0, pkz;
#pragma unroll
      for (int r = 0; r < 4; ++r) {
        float sv = (g == 0 && r == 0) ? s0[r] : -1e30f;
        float p = fexp2(sv);
        rs += p;
        pk0[r] = f2bf(p);
        pkz[r] = 0;
      }
      *(short4v*)PW0 = pk0; *(short4v*)PW1 = pkz;
      rs += __shfl_xor(rs, 16);
      rs += __shfl_xor(rs, 32);
      ls += rs;
      bf16x8 pa0 = *(const bf16x8*)PR0;
#pragma unroll
      for (int nd = 0; nd < 4; ++nd)
        accd[nd] = mfma16(pa0, *(const bf16x8*)(Vf0 + nd * 1024), accd[nd]);
    };
    one(qf0a, qf1a, accA, lsA);
    one(qf0b, qf1b, accB, lsB);
  };

  stage(Kd0, Vd0);
  __syncthreads();
#pragma unroll 1
  for (int t2 = 0; t2 < 5; ++t2) {
    stage(Kd1, Vd1);
    tilestep(KF00, KF01, VF00, VF01);
    __syncthreads();
    if (t2 < 4) {
      stage(Kd0, Vd0);
      tilestep(KF10, KF11, VF10, VF11);
      __syncthreads();
    }
  }
  lasttile(KF10, KF11, VF10);          // tile 9 (keys 576..639; 1 valid)

  auto epi = [&](f32x4* accd, float ls, int qt) {
    float ls4[4];
#pragma unroll
    for (int r = 0; r < 4; ++r) ls4[r] = __shfl(ls, (g << 2) + r);
#pragma unroll
    for (int r = 0; r < 4; ++r) {
      int qr = qt * 64 + w * 16 + (g << 2) + r;
      if (qr < Nn) {
        float inv = 1.0f / ls4[r];
        size_t base = ((size_t)(bb * Nn + qr)) * Cc + hh * DK;
#pragma unroll
        for (int nd = 0; nd < 4; ++nd)
          ao[base + nd * 16 + qi] = f2bf(accd[nd][r] * inv);
      }
    }
  };
  epi(accA, lsA, qt0);
  epi(accB, lsB, qt0 + 1);
}

// ---------------- launch ----------------

extern "C" void kernel_launch(void* const* d_in, const int* in_sizes, int n_in,
                              void* d_out, int out_size, void* d_ws, size_t ws_size,
                              hipStream_t stream) {
  const float* x  = (const float*)d_in[0];
  const float* Wq = (const float*)d_in[1];
  const float* bq = (const float*)d_in[2];
  const float* Wk = (const float*)d_in[3];
  const float* bk = (const float*)d_in[4];
  const float* Wv = (const float*)d_in[5];
  const float* bv = (const float*)d_in[6];
  const float* Wo = (const float*)d_in[7];
  const float* bo = (const float*)d_in[8];
  float* out = (float*)d_out;

  char* ws = (char*)d_ws;
  size_t off = 0;
  auto alloc = [&](size_t bytes) {
    char* p = ws + off;
    off += (bytes + 255) & ~(size_t)255;
    return p;
  };
  short* xb   = (short*)alloc((size_t)Mm * Cc * 2);          // x bf16 (reused as attn_out)
  short* wqkv = (short*)alloc((size_t)NQKV * Cc * 2);
  short* wob  = (short*)alloc((size_t)Cc * Cc * 2);
  short* qb   = (short*)alloc((size_t)Bb * Hh * Nn * DK * 2);
  short* kb   = (short*)alloc((size_t)Bb * Hh * Nn * DK * 2);
  short* vb   = (short*)alloc((size_t)Bb * Hh * Nn * DK * 2);
  short* vtb  = (short*)alloc((size_t)Bb * Hh * DK * NKPAD * 2);
  short* aob  = xb;   // x_bf16 dead after GEMM1; alias for attn output

  k_cvt_all<<<4096, 256, 0, stream>>>(x, Wq, Wk, Wv, Wo, xb, wqkv, wob);

  const int nbm = (Mm + 255) / 256;        // 73
  k_gemm_qkv<<<nbm * (NQKV / 256), 512, 0, stream>>>(xb, wqkv, bq, bk, bv, qb, kb, vb);

  k_transpose_v<<<Bb * Hh * NT, 256, 0, stream>>>(vb, vtb);

  k_attn<<<Bb * Hh * 5, 256, 0, stream>>>(qb, kb, vtb, aob);

  k_gemm_out<<<nbm * (Cc / 256), 512, 0, stream>>>(aob, wob, bo, out);
}

// Round 15
// 187.847 us; speedup vs baseline: 1.1724x; 1.0631x over previous
//
#include <hip/hip_runtime.h>
#include <cstdint>
#include <cstddef>
#include <cstring>

typedef float  f32x4   __attribute__((ext_vector_type(4)));
typedef __bf16 bf16x8  __attribute__((ext_vector_type(8)));
typedef short  short8  __attribute__((ext_vector_type(8)));
typedef short  short4v __attribute__((ext_vector_type(4)));
typedef float  float4v __attribute__((ext_vector_type(4)));

#define DEVI __device__ __forceinline__

constexpr int Bb = 32, Nn = 577, Cc = 768, Hh = 12, DK = 64;
constexpr int Mm   = Bb * Nn;     // 18464 rows
constexpr int NQKV = 3 * Cc;      // 2304 fused QKV output cols
constexpr int NKPAD = 640;        // padded key count (10 tiles of 64)
constexpr int NT = 10;
#define QSCALE 0.1803368926f      // 0.125 * log2(e) folded into Q

DEVI short f2bf(float f) {
  __bf16 h = (__bf16)f;
  short s;
  __builtin_memcpy(&s, &h, 2);
  return s;
}

DEVI float fexp2(float x) { return __builtin_amdgcn_exp2f(x); }  // bare v_exp_f32

DEVI void gload16(const short* g, short* l) {   // async global->LDS, 16B/lane
  __builtin_amdgcn_global_load_lds(
      (const __attribute__((address_space(1))) void*)g,
      (__attribute__((address_space(3))) void*)l, 16, 0, 0);
}

DEVI f32x4 mfma16(bf16x8 a, bf16x8 b, f32x4 c) {
  return __builtin_amdgcn_mfma_f32_16x16x32_bf16(a, b, c, 0, 0, 0);
}

// XCD-bijective chunking over Triton-style grouped ordering.
DEVI void remap_grouped(int bid, int nbm, int nbn, int GM, int& bm, int& bn) {
  const int nwg = nbm * nbn;
  const int xcd = bid & 7, j = bid >> 3;
  const int q = nwg >> 3, r = nwg & 7;
  int wg = (xcd < r ? xcd * (q + 1) : r * (q + 1) + (xcd - r) * q) + j;
  const int per = GM * nbn;
  int grp = wg / per;
  int first = grp * GM;
  int sz = min(GM, nbm - first);
  int rem = wg - grp * per;
  bm = first + rem % sz;
  bn = rem / sz;
}

// ---------------- single fused conversion kernel (grid-stride, G11) ----------

__global__ void k_cvt_all(const float* __restrict__ x,
                          const float* __restrict__ Wq, const float* __restrict__ Wk,
                          const float* __restrict__ Wv, const float* __restrict__ Wo,
                          short* __restrict__ xb, short* __restrict__ wqkv,
                          short* __restrict__ wob) {
  const int NX4   = Mm * Cc / 4;        // float4s of x
  const int WSZ4  = Cc * Cc / 4;        // per weight matrix
  const int NTOT  = NX4 + 4 * WSZ4;
  for (int i = blockIdx.x * 256 + threadIdx.x; i < NTOT; i += gridDim.x * 256) {
    const float* src;
    short* dst;
    int e;
    if (i < NX4) { src = x; dst = xb; e = i; }
    else {
      int j = i - NX4;
      if (j < WSZ4)          { src = Wq; dst = wqkv;                e = j; }
      else if (j < 2 * WSZ4) { src = Wk; dst = wqkv + WSZ4 * 4;     e = j - WSZ4; }
      else if (j < 3 * WSZ4) { src = Wv; dst = wqkv + 2 * WSZ4 * 4; e = j - 2 * WSZ4; }
      else                   { src = Wo; dst = wob;                 e = j - 3 * WSZ4; }
    }
    float4v v = *(const float4v*)(src + (size_t)e * 4);
    short4v o;
#pragma unroll
    for (int t = 0; t < 4; ++t) o[t] = f2bf(v[t]);
    *(short4v*)(dst + (size_t)e * 4) = o;
  }
}

#define WAITV(N) asm volatile("s_waitcnt vmcnt(" #N ")" ::: "memory")

// ============ core B: [256][64]-row tiles, 8-granule XOR (0-conflict), 8-phase
// schedule (R11/R13-validated best).
#define GPH(BUF, KK, MH, STAGE, WAIT)                                      \
  {                                                                        \
    const short* Ab_ = Al + (BUF) * 16384;                                 \
    const short* Bb_ = Bl + (BUF) * 16384;                                 \
    bf16x8 af_[4];                                                         \
    _Pragma("unroll")                                                      \
    for (int m_ = 0; m_ < 4; ++m_)                                         \
      af_[m_] = *(const bf16x8*)(Ab_ + (offA[(MH) * 4 + m_] ^ ((KK) * 32))); \
    if ((MH) == 0) {                                                       \
      _Pragma("unroll")                                                    \
      for (int n_ = 0; n_ < 4; ++n_)                                       \
        bfr[n_] = *(const bf16x8*)(Bb_ + (offB[n_] ^ ((KK) * 32)));        \
    }                                                                      \
    STAGE;                                                                 \
    WAIT;                                                                  \
    __builtin_amdgcn_s_barrier();                                          \
    __builtin_amdgcn_s_setprio(1);                                         \
    _Pragma("unroll")                                                      \
    for (int m_ = 0; m_ < 4; ++m_)                                         \
      _Pragma("unroll")                                                    \
      for (int n_ = 0; n_ < 4; ++n_)                                       \
        acc[(MH) * 4 + m_][n_] = mfma16(af_[m_], bfr[n_], acc[(MH) * 4 + m_][n_]); \
    __builtin_amdgcn_s_setprio(0);                                         \
    __builtin_amdgcn_s_barrier();                                          \
  }

DEVI void gemm256b(const short* __restrict__ A, const short* __restrict__ Bm,
                   int arows, int bm, int bn,
                   short* Al, short* Bl, f32x4 acc[8][4]) {
  const int tid = threadIdx.x;               // 0..511
  const int lane = tid & 63, w = tid >> 6;
  const int wm = w >> 2, wn = w & 3;
  const int qi = lane & 15, g = lane >> 4;

#pragma unroll
  for (int m = 0; m < 8; ++m)
#pragma unroll
    for (int n = 0; n < 4; ++n) acc[m][n] = (f32x4)0.0f;

  const int rloc = tid >> 3, c8 = tid & 7;
  const int gswz = (c8 ^ (rloc & 7)) * 8;
  const short* pA[4];
  const short* pB[4];
#pragma unroll
  for (int s = 0; s < 4; ++s) {
    int ra = bm * 256 + s * 64 + rloc; if (ra > arows - 1) ra = arows - 1;
    pA[s] = A  + (size_t)ra * Cc + gswz;
    pB[s] = Bm + (size_t)(bn * 256 + s * 64 + rloc) * Cc + gswz;
  }
  auto stA = [&](int buf, int s, int co) {
    gload16(pA[s] + co, Al + buf * 16384 + s * 4096 + tid * 8);
  };
  auto stB = [&](int buf, int s, int co) {
    gload16(pB[s] + co, Bl + buf * 16384 + s * 4096 + tid * 8);
  };

  int offA[8], offB[4];
#pragma unroll
  for (int m = 0; m < 8; ++m) {
    int r = wm * 128 + m * 16 + qi;
    offA[m] = r * 64 + ((g ^ (r & 7)) * 8);
  }
#pragma unroll
  for (int n = 0; n < 4; ++n) {
    int r = wn * 64 + n * 16 + qi;
    offB[n] = r * 64 + ((g ^ (r & 7)) * 8);
  }
  bf16x8 bfr[4];

  // prologue: tile0 A+B (8 segs), tile1 B{0,1}; WAITV(2) -> tile0 resident
  stA(0, 0, 0); stA(0, 1, 0); stA(0, 2, 0); stA(0, 3, 0);
  stB(0, 0, 0); stB(0, 1, 0); stB(0, 2, 0); stB(0, 3, 0);
  stB(1, 0, 64); stB(1, 1, 64);
  WAITV(2);
  __builtin_amdgcn_s_barrier();

#pragma unroll 1
  for (int i = 0; i < 5; ++i) {
    const int cb1  = 64 + 128 * i;     // tile 2i+1 cols
    const int cb0n = cb1 + 64;         // tile 2i+2
    const int cb1n = cb1 + 128;        // tile 2i+3
    GPH(0, 0, 0, (stB(1, 2, cb1),  stB(1, 3, cb1)),  (void)0);
    GPH(0, 0, 1, (stA(1, 0, cb1),  stA(1, 2, cb1)),  (void)0);
    GPH(0, 1, 0, (stA(1, 1, cb1),  stA(1, 3, cb1)),  (void)0);
    GPH(0, 1, 1, (stA(0, 0, cb0n), stA(0, 2, cb0n)), WAITV(4));
    GPH(1, 0, 0, (stA(0, 1, cb0n), stA(0, 3, cb0n)), WAITV(4));
    GPH(1, 0, 1, (stB(0, 0, cb0n), stB(0, 1, cb0n)), (void)0);
    GPH(1, 1, 0, (stB(0, 2, cb0n), stB(0, 3, cb0n)), (void)0);
    GPH(1, 1, 1, (stB(1, 0, cb1n), stB(1, 1, cb1n)), WAITV(2));
  }
  // tail: tiles 10 (buf0), 11 (buf1); finish staging tile 11 (col 704)
  GPH(0, 0, 0, (stB(1, 2, 704), stB(1, 3, 704)), (void)0);
  GPH(0, 0, 1, (stA(1, 0, 704), stA(1, 2, 704)), (void)0);
  GPH(0, 1, 0, (stA(1, 1, 704), stA(1, 3, 704)), (void)0);
  GPH(0, 1, 1, (void)0, WAITV(2));
  GPH(1, 0, 0, (void)0, WAITV(0));
  GPH(1, 0, 1, (void)0, (void)0);
  GPH(1, 1, 0, (void)0, (void)0);
  GPH(1, 1, 1, (void)0, (void)0);
}

// GEMM1: x_bf16 @ [Wq;Wk;Wv]^T + b -> q/k [B,H,N,64] bf16 (Q scaled); V is
// written DIRECTLY TRANSPOSED to vt [B,H,64,640] via per-wave LDS scratch
// (Al/Bl dead after final GPH barrier; proj==2 <=> bn>=6 is block-uniform and
// each wave's 64 cols = one full head's d-range).
__global__ __launch_bounds__(512) void k_gemm_qkv(
    const short* __restrict__ A, const short* __restrict__ Bm,
    const float* __restrict__ bq, const float* __restrict__ bk, const float* __restrict__ bv,
    short* __restrict__ qv, short* __restrict__ kv, short* __restrict__ vt) {
  __shared__ short Al[2 * 16384];
  __shared__ short Bl[2 * 16384];
  int bm, bn;
  remap_grouped((int)blockIdx.x, (Mm + 255) / 256, NQKV / 256, 4, bm, bn);
  f32x4 acc[8][4];
  gemm256b(A, Bm, Mm, bm, bn, Al, Bl, acc);

  const int lane = threadIdx.x & 63, w = threadIdx.x >> 6;
  const int wm = w >> 2, wn = w & 3;
  const int qi = lane & 15, g = lane >> 4;
  const int cb = bn * 256 + wn * 64;         // 64-aligned -> single (proj, head)
  const int proj = cb / Cc;
  const int within = cb - proj * Cc;
  const int hh = within >> 6;

  if (proj < 2) {
    const float* bias = proj == 0 ? bq : bk;
    short* dst = proj == 0 ? qv : kv;
    const float sc = proj == 0 ? QSCALE : 1.0f;
    float bvv[4];
#pragma unroll
    for (int n = 0; n < 4; ++n) bvv[n] = bias[within + n * 16 + qi];
#pragma unroll
    for (int m = 0; m < 8; ++m)
#pragma unroll
      for (int r = 0; r < 4; ++r) {
        int row = bm * 256 + wm * 128 + m * 16 + g * 4 + r;
        if (row < Mm) {
          int b = row / Nn;
          int nn = row - b * Nn;
          size_t base = ((size_t)(b * Hh + hh) * Nn + nn) * DK;
#pragma unroll
          for (int n = 0; n < 4; ++n)
            dst[base + n * 16 + qi] = f2bf((acc[m][n][r] + bvv[n]) * sc);
        }
      }
  } else {
    // ---- V: fused transpose through per-wave LDS scratch (16KB each) ----
    float bvv[4];
#pragma unroll
    for (int n = 0; n < 4; ++n) bvv[n] = bv[within + n * 16 + qi];
    short* sc = (w < 4 ? Al : Bl) + (w & 3) * 8192;   // [64 d][128 tok], XOR-swz
    const int dq = qi & 7;
#pragma unroll
    for (int m = 0; m < 8; ++m)
#pragma unroll
      for (int n = 0; n < 4; ++n) {
        int d = n * 16 + qi;
        short4v pk;
#pragma unroll
        for (int r = 0; r < 4; ++r) pk[r] = f2bf(acc[m][n][r] + bvv[n]);
        int g8 = 2 * m + (g >> 1);                    // 8-short granule of tok
        *(short4v*)(sc + d * 128 + ((g8 ^ dq) << 3) + ((g & 1) << 2)) = pk;
      }
    // same-wave DS ordering: write->read safe without barrier
#pragma unroll
    for (int it = 0; it < 16; ++it) {
      int G = it * 64 + lane;
      int d = G >> 4, cg = G & 15;
      short8 v = *(const short8*)(sc + d * 128 + ((cg ^ (d & 7)) << 3));
      int tokg = bm * 256 + wm * 128 + cg * 8;
      if (tokg < Mm) {
        int b0 = tokg / Nn, nn0 = tokg - b0 * Nn;
        if (nn0 + 8 <= Nn) {
          __builtin_memcpy(vt + ((size_t)(b0 * Hh + hh) * DK + d) * NKPAD + nn0, &v, 16);
        } else {
#pragma unroll
          for (int j = 0; j < 8; ++j) {
            int tg = tokg + j;
            if (tg < Mm) {
              int b1 = tg / Nn, nn1 = tg - b1 * Nn;
              vt[((size_t)(b1 * Hh + hh) * DK + d) * NKPAD + nn1] = v[j];
            }
          }
        }
      }
    }
  }
}

// GEMM2: attn_out_bf16 @ Wo^T + bo -> fp32 out [M][768]
__global__ __launch_bounds__(512) void k_gemm_out(
    const short* __restrict__ A, const short* __restrict__ Bm,
    const float* __restrict__ bo, float* __restrict__ out) {
  __shared__ short Al[2 * 16384];
  __shared__ short Bl[2 * 16384];
  int bm, bn;
  remap_grouped((int)blockIdx.x, (Mm + 255) / 256, Cc / 256, 8, bm, bn);
  f32x4 acc[8][4];
  gemm256b(A, Bm, Mm, bm, bn, Al, Bl, acc);

  const int lane = threadIdx.x & 63, w = threadIdx.x >> 6;
  const int wm = w >> 2, wn = w & 3;
  const int qi = lane & 15, g = lane >> 4;
  const int cb = bn * 256 + wn * 64;
  float bvv[4];
#pragma unroll
  for (int n = 0; n < 4; ++n) bvv[n] = bo[cb + n * 16 + qi];
#pragma unroll
  for (int m = 0; m < 8; ++m)
#pragma unroll
    for (int r = 0; r < 4; ++r) {
      int row = bm * 256 + wm * 128 + m * 16 + g * 4 + r;
      if (row < Mm) {
#pragma unroll
        for (int n = 0; n < 4; ++n)
          out[(size_t)row * Cc + cb + n * 16 + qi] = acc[m][n][r] + bvv[n];
      }
    }
}

// Flash attention: swapped-QK^T, no-max softmax, 2 q-tiles/block, K/V frags
// register-shared across q-tiles, ONE shared P buffer (40KB LDS). Last key
// tile (1 valid key of 64) runs a specialized cheap path. Pad keys 577..639
// of vt are never written (poison bf16 is finite; killed by P=0 masking).
__global__ __launch_bounds__(256) void k_attn(const short* __restrict__ q,
                                              const short* __restrict__ k,
                                              const short* __restrict__ vt,
                                              short* __restrict__ ao) {
  __shared__ short Ks[2][64 * 64];
  __shared__ short Vs[2][64 * 64];
  __shared__ short Ps[4][16 * 64];     // per-wave, shared by both q-tiles
  int bid = (int)blockIdx.x;
  bid = (bid & 7) * 240 + (bid >> 3);  // XCD swizzle: 1920 = 8*240, bijective
  const int qtp = bid % 5, bh = bid / 5;
  const int qt0 = qtp * 2;
  const int bb = bh / Hh, hh = bh - bb * Hh;
  const int tid = threadIdx.x, lane = tid & 63, w = tid >> 6;
  const int qi = lane & 15, g = lane >> 4;

  const short* qb  = q  + (size_t)bh * Nn * DK;
  const short* kb  = k  + (size_t)bh * Nn * DK;
  const short* vtb = vt + (size_t)bh * DK * NKPAD;

  const int qrow = qt0 * 64 + w * 16 + qi;
  const bf16x8 qf0a = *(const bf16x8*)(qb + (size_t)qrow * DK + g * 8);
  const bf16x8 qf1a = *(const bf16x8*)(qb + (size_t)qrow * DK + 32 + g * 8);
  const bf16x8 qf0b = *(const bf16x8*)(qb + (size_t)(qrow + 64) * DK + g * 8);
  const bf16x8 qf1b = *(const bf16x8*)(qb + (size_t)(qrow + 64) * DK + 32 + g * 8);

  const int r0 = tid >> 3, cc = tid & 7;
  const int cs0 = (cc ^ (r0 & 7)) * 8;
  const short* kg = kb + r0 * DK + cs0;
  const short* vg = vtb + (size_t)r0 * NKPAD + cs0;
  short* const Kd0 = &Ks[0][w * 512]; short* const Kd1 = &Ks[1][w * 512];
  short* const Vd0 = &Vs[0][w * 512]; short* const Vd1 = &Vs[1][w * 512];

  auto stage = [&](short* Kd, short* Vd) {
    gload16(kg, Kd);          gload16(kg + 2048,  Kd + 2048);
    gload16(vg, Vd);          gload16(vg + 20480, Vd + 2048);
    kg += 4096;               vg += 64;
  };

  const int swq = qi & 7;
  const short* const KF00 = &Ks[0][qi * 64 + ((g    ) ^ swq) * 8];
  const short* const KF01 = &Ks[0][qi * 64 + ((g + 4) ^ swq) * 8];
  const short* const KF10 = &Ks[1][qi * 64 + ((g    ) ^ swq) * 8];
  const short* const KF11 = &Ks[1][qi * 64 + ((g + 4) ^ swq) * 8];
  const short* const VF00 = &Vs[0][qi * 64 + ((g    ) ^ swq) * 8];
  const short* const VF01 = &Vs[0][qi * 64 + ((g + 4) ^ swq) * 8];
  const short* const VF10 = &Vs[1][qi * 64 + ((g    ) ^ swq) * 8];
  const short* const VF11 = &Vs[1][qi * 64 + ((g + 4) ^ swq) * 8];
  short* const PW0 = &Ps[w][qi * 64 + (((0  + g) ^ (swq << 1)) << 2)];
  short* const PW1 = &Ps[w][qi * 64 + (((4  + g) ^ (swq << 1)) << 2)];
  short* const PW2 = &Ps[w][qi * 64 + (((8  + g) ^ (swq << 1)) << 2)];
  short* const PW3 = &Ps[w][qi * 64 + (((12 + g) ^ (swq << 1)) << 2)];
  const short* const PR0 = &Ps[w][qi * 64 + ((g    ) ^ swq) * 8];
  const short* const PR1 = &Ps[w][qi * 64 + ((g + 4) ^ swq) * 8];

  f32x4 accA[4], accB[4];
#pragma unroll
  for (int nd = 0; nd < 4; ++nd) { accA[nd] = (f32x4)0.0f; accB[nd] = (f32x4)0.0f; }
  float lsA = 0.f, lsB = 0.f;

  auto smax = [&](f32x4* s, float& ls) {
    float rs = 0.f;
    short4v pk0, pk1, pk2, pk3;
#pragma unroll
    for (int r = 0; r < 4; ++r) { float p = fexp2(s[0][r]); rs += p; pk0[r] = f2bf(p); }
#pragma unroll
    for (int r = 0; r < 4; ++r) { float p = fexp2(s[1][r]); rs += p; pk1[r] = f2bf(p); }
#pragma unroll
    for (int r = 0; r < 4; ++r) { float p = fexp2(s[2][r]); rs += p; pk2[r] = f2bf(p); }
#pragma unroll
    for (int r = 0; r < 4; ++r) { float p = fexp2(s[3][r]); rs += p; pk3[r] = f2bf(p); }
    *(short4v*)PW0 = pk0; *(short4v*)PW1 = pk1;
    *(short4v*)PW2 = pk2; *(short4v*)PW3 = pk3;
    rs += __shfl_xor(rs, 16);
    rs += __shfl_xor(rs, 32);
    ls += rs;
  };

  auto tilestep = [&](const short* Kf0, const short* Kf1,
                      const short* Vf0, const short* Vf1) {
    f32x4 sA[4], sB[4];
#pragma unroll
    for (int ni = 0; ni < 4; ++ni) { sA[ni] = (f32x4)0.0f; sB[ni] = (f32x4)0.0f; }
    {
      bf16x8 kf[4];
#pragma unroll
      for (int ni = 0; ni < 4; ++ni) kf[ni] = *(const bf16x8*)(Kf0 + ni * 1024);
#pragma unroll
      for (int ni = 0; ni < 4; ++ni) sA[ni] = mfma16(kf[ni], qf0a, sA[ni]);
#pragma unroll
      for (int ni = 0; ni < 4; ++ni) sB[ni] = mfma16(kf[ni], qf0b, sB[ni]);
#pragma unroll
      for (int ni = 0; ni < 4; ++ni) kf[ni] = *(const bf16x8*)(Kf1 + ni * 1024);
#pragma unroll
      for (int ni = 0; ni < 4; ++ni) sA[ni] = mfma16(kf[ni], qf1a, sA[ni]);
#pragma unroll
      for (int ni = 0; ni < 4; ++ni) sB[ni] = mfma16(kf[ni], qf1b, sB[ni]);
    }
    smax(sA, lsA);
    bf16x8 paA0 = *(const bf16x8*)PR0;   // reads issued before P is overwritten
    bf16x8 paA1 = *(const bf16x8*)PR1;
    smax(sB, lsB);
    bf16x8 paB0 = *(const bf16x8*)PR0;
    bf16x8 paB1 = *(const bf16x8*)PR1;
    {
      bf16x8 vf[4];
#pragma unroll
      for (int nd = 0; nd < 4; ++nd) vf[nd] = *(const bf16x8*)(Vf0 + nd * 1024);
#pragma unroll
      for (int nd = 0; nd < 4; ++nd) accA[nd] = mfma16(paA0, vf[nd], accA[nd]);
#pragma unroll
      for (int nd = 0; nd < 4; ++nd) accB[nd] = mfma16(paB0, vf[nd], accB[nd]);
#pragma unroll
      for (int nd = 0; nd < 4; ++nd) vf[nd] = *(const bf16x8*)(Vf1 + nd * 1024);
#pragma unroll
      for (int nd = 0; nd < 4; ++nd) accA[nd] = mfma16(paA1, vf[nd], accA[nd]);
#pragma unroll
      for (int nd = 0; nd < 4; ++nd) accB[nd] = mfma16(paB1, vf[nd], accB[nd]);
    }
  };

  // Specialized last tile: only key 576 (tile-local 0) valid.
  auto lasttile = [&](const short* Kf0, const short* Kf1,
                      const short* Vf0) {
    auto one = [&](const bf16x8& qf0, const bf16x8& qf1, f32x4* accd, float& ls) {
      f32x4 s0 = (f32x4)0.0f;
      s0 = mfma16(*(const bf16x8*)(Kf0), qf0, s0);
      s0 = mfma16(*(const bf16x8*)(Kf1), qf1, s0);
      float rs = 0.f;
      short4v pk0, pkz;
#pragma unroll
      for (int r = 0; r < 4; ++r) {
        float sv = (g == 0 && r == 0) ? s0[r] : -1e30f;
        float p = fexp2(sv);
        rs += p;
        pk0[r] = f2bf(p);
        pkz[r] = 0;
      }
      *(short4v*)PW0 = pk0; *(short4v*)PW1 = pkz;
      rs += __shfl_xor(rs, 16);
      rs += __shfl_xor(rs, 32);
      ls += rs;
      bf16x8 pa0 = *(const bf16x8*)PR0;
#pragma unroll
      for (int nd = 0; nd < 4; ++nd)
        accd[nd] = mfma16(pa0, *(const bf16x8*)(Vf0 + nd * 1024), accd[nd]);
    };
    one(qf0a, qf1a, accA, lsA);
    one(qf0b, qf1b, accB, lsB);
  };

  stage(Kd0, Vd0);
  __syncthreads();
#pragma unroll 1
  for (int t2 = 0; t2 < 5; ++t2) {
    stage(Kd1, Vd1);
    tilestep(KF00, KF01, VF00, VF01);
    __syncthreads();
    if (t2 < 4) {
      stage(Kd0, Vd0);
      tilestep(KF10, KF11, VF10, VF11);
      __syncthreads();
    }
  }
  lasttile(KF10, KF11, VF10);          // tile 9 (keys 576..639; 1 valid)

  auto epi = [&](f32x4* accd, float ls, int qt) {
    float ls4[4];
#pragma unroll
    for (int r = 0; r < 4; ++r) ls4[r] = __shfl(ls, (g << 2) + r);
#pragma unroll
    for (int r = 0; r < 4; ++r) {
      int qr = qt * 64 + w * 16 + (g << 2) + r;
      if (qr < Nn) {
        float inv = 1.0f / ls4[r];
        size_t base = ((size_t)(bb * Nn + qr)) * Cc + hh * DK;
#pragma unroll
        for (int nd = 0; nd < 4; ++nd)
          ao[base + nd * 16 + qi] = f2bf(accd[nd][r] * inv);
      }
    }
  };
  epi(accA, lsA, qt0);
  epi(accB, lsB, qt0 + 1);
}

// ---------------- launch ----------------

extern "C" void kernel_launch(void* const* d_in, const int* in_sizes, int n_in,
                              void* d_out, int out_size, void* d_ws, size_t ws_size,
                              hipStream_t stream) {
  const float* x  = (const float*)d_in[0];
  const float* Wq = (const float*)d_in[1];
  const float* bq = (const float*)d_in[2];
  const float* Wk = (const float*)d_in[3];
  const float* bk = (const float*)d_in[4];
  const float* Wv = (const float*)d_in[5];
  const float* bv = (const float*)d_in[6];
  const float* Wo = (const float*)d_in[7];
  const float* bo = (const float*)d_in[8];
  float* out = (float*)d_out;

  char* ws = (char*)d_ws;
  size_t off = 0;
  auto alloc = [&](size_t bytes) {
    char* p = ws + off;
    off += (bytes + 255) & ~(size_t)255;
    return p;
  };
  short* xb   = (short*)alloc((size_t)Mm * Cc * 2);          // x bf16 (reused as attn_out)
  short* wqkv = (short*)alloc((size_t)NQKV * Cc * 2);
  short* wob  = (short*)alloc((size_t)Cc * Cc * 2);
  short* qb   = (short*)alloc((size_t)Bb * Hh * Nn * DK * 2);
  short* kb   = (short*)alloc((size_t)Bb * Hh * Nn * DK * 2);
  short* vtb  = (short*)alloc((size_t)Bb * Hh * DK * NKPAD * 2);
  short* aob  = xb;   // x_bf16 dead after GEMM1; alias for attn output

  k_cvt_all<<<4096, 256, 0, stream>>>(x, Wq, Wk, Wv, Wo, xb, wqkv, wob);

  const int nbm = (Mm + 255) / 256;        // 73
  k_gemm_qkv<<<nbm * (NQKV / 256), 512, 0, stream>>>(xb, wqkv, bq, bk, bv, qb, kb, vtb);

  k_attn<<<Bb * Hh * 5, 256, 0, stream>>>(qb, kb, vtb, aob);

  k_gemm_out<<<nbm * (Cc / 256), 512, 0, stream>>>(aob, wob, bo, out);
}